// Round 11
// baseline (1270.214 us; speedup 1.0000x reference)
//
#include <hip/hip_runtime.h>
#include <math.h>

typedef unsigned short u16;
typedef u16 u16x8 __attribute__((ext_vector_type(8)));
typedef __bf16 bf16x8 __attribute__((ext_vector_type(8)));
typedef float f32x4 __attribute__((ext_vector_type(4)));

#define HID 200
#define G4H 800
#define TLEN 128
#define LATENT 128
#define NCODES 1024
#define DIN 768
#define DCOND 1536
#define NB 256
#define MROWS (NB * TLEN)
#define LDG 896
#define LDH1 256
#define LDH2 512
#define NOUT 768

__device__ __forceinline__ u16 f2b(float f) {
  union { float f; unsigned u; } v; v.f = f;
  unsigned r = v.u + 0x7fffu + ((v.u >> 16) & 1u);
  return (u16)(r >> 16);
}
__device__ __forceinline__ float b2f(u16 h) {
  union { unsigned u; float f; } v; v.u = ((unsigned)h) << 16;
  return v.f;
}
__device__ __forceinline__ float sigf(float x) { return 1.f / (1.f + __expf(-x)); }
__device__ __forceinline__ float tanh_fast(float x) {
  return 1.f - 2.f / (__expf(2.f * x) + 1.f);
}

// async global->LDS, 16B per lane
__device__ __forceinline__ void gl16(const void* g, void* l) {
  __builtin_amdgcn_global_load_lds(
      (const __attribute__((address_space(1))) void*)g,
      (__attribute__((address_space(3))) void*)l, 16, 0, 0);
}

__device__ __forceinline__ unsigned cvtpk(float a, float b) {
  unsigned r;
  asm("v_cvt_pk_bf16_f32 %0, %1, %2" : "=v"(r) : "v"(a), "v"(b));
  return r;
}

// unpack 4 bf16 (as uint2) -> f32x4
__device__ __forceinline__ f32x4 gx4(uint2 u) {
  union { unsigned q; float f; } a;
  f32x4 r;
  a.q = u.x << 16;          r.x = a.f;
  a.q = u.x & 0xFFFF0000u;  r.y = a.f;
  a.q = u.y << 16;          r.z = a.f;
  a.q = u.y & 0xFFFF0000u;  r.w = a.f;
  return r;
}

// ---------------- weight convert + pad ----------------
__global__ void cvt_pad(const float* __restrict__ src, u16* __restrict__ dst,
                        int nr, int nc, int lds, int col0, int NRp, int KP) {
  int i = blockIdx.x * blockDim.x + threadIdx.x;
  if (i >= NRp * KP) return;
  int r = i / KP, c = i - r * KP;
  float v = (r < nr && c < nc) ? src[(size_t)r * lds + col0 + c] : 0.f;
  dst[i] = f2b(v);
}

__global__ void pad_f32(const float* __restrict__ src, float* __restrict__ dst,
                        int n, int npad) {
  int i = blockIdx.x * blockDim.x + threadIdx.x;
  if (i < npad) dst[i] = (i < n) ? src[i] : 0.f;
}

// biasc[col<896] = b_ih + b_hh (0-padded)
__global__ void bias_pack(const float* __restrict__ b_ih, const float* __restrict__ b_hh,
                          float* __restrict__ biasc) {
  int i = blockIdx.x * blockDim.x + threadIdx.x;
  if (i < LDG) biasc[i] = (i < G4H) ? (b_ih[i] + b_hh[i]) : 0.f;
}

// W_hh [800][200] f32 -> MFMA A-fragments, bf16.
// Wf[((w*8+tt)*7+f)*64 + l]: tile tt: gate=tt>>1, s=tt&1; row u=w*32+s*16+(l&15)
// (pad u>=200 -> 0); k = f*32 + (l>>4)*8 + 2d+{0,1} (pad k>=200 -> 0).
__global__ void pack_wf(const float* __restrict__ Whh, uint4* __restrict__ Wf) {
  int i = blockIdx.x * blockDim.x + threadIdx.x;
  if (i >= 56 * 64) return;
  int l = i & 63, rest = i >> 6;
  int f = rest % 7, tt = (rest / 7) & 7, w = rest / 56;
  int gate = tt >> 1, s = tt & 1;
  int u = w * 32 + s * 16 + (l & 15);
  int kbase = f * 32 + (l >> 4) * 8;
  unsigned out[4];
#pragma unroll
  for (int d = 0; d < 4; ++d) {
    unsigned lo = 0, hi = 0;
    int k0 = kbase + 2 * d, k1 = k0 + 1;
    if (u < HID) {
      const float* row = Whh + (size_t)(gate * HID + u) * HID;
      if (k0 < HID) lo = f2b(row[k0]);
      if (k1 < HID) hi = f2b(row[k1]);
    }
    out[d] = lo | (hi << 16);
  }
  uint4 o; o.x = out[0]; o.y = out[1]; o.z = out[2]; o.w = out[3];
  Wf[i] = o;
}

// ---------------- bf16 MFMA GEMM: C[M,N] = A[M,K] * B[N,K]^T (+epilogue) ----------------
enum { EPI_GATES = 0, EPI_H1 = 1, EPI_H2 = 2, EPI_OUT = 3 };

__device__ __forceinline__ f32x4 mfma16(bf16x8 a, bf16x8 b, f32x4 c) {
  return __builtin_amdgcn_mfma_f32_16x16x32_bf16(a, b, c, 0, 0, 0);
}

template<bool AF32, int EPI>
__global__ __launch_bounds__(256) void gemm_bf16(
    const void* __restrict__ Ap, const u16* __restrict__ Bp,
    void* __restrict__ Cp, int K, int ldc, const float* __restrict__ bias) {
  __shared__ __attribute__((aligned(16))) char AsRaw[AF32 ? 128 * 32 * 4 : 128 * 32 * 2];
  __shared__ __attribute__((aligned(16))) u16 Bs[128 * 32];
  float* Asf = (float*)AsRaw;
  u16* As16 = (u16*)AsRaw;

  const int t = threadIdx.x;
  const int tileN = blockIdx.x * 128;
  const int tileM = blockIdx.y * 128;
  const int l = t & 63;
  const int w = t >> 6;
  const int wr = (w >> 1) * 64;
  const int wc = (w & 1) * 64;
  const int fr = l & 15;
  const int fg = l >> 4;

  const u16* bsrc[2];
  u16* bdst[2];
#pragma unroll
  for (int j = 0; j < 2; ++j) {
    int tb = w * 1024 + j * 4096 + (t & 63) * 16;
    int row = tb >> 6, gd = (tb >> 4) & 3;
    bsrc[j] = Bp + (size_t)(tileN + row) * K + ((gd ^ ((row >> 1) & 3)) << 3);
    bdst[j] = Bs + w * 512 + j * 2048;
  }
  const float* asrcF[4];
  float* adstF[4];
  const u16* asrcH[2];
  u16* adstH[2];
  if constexpr (AF32) {
#pragma unroll
    for (int j = 0; j < 4; ++j) {
      int tb = w * 1024 + j * 4096 + (t & 63) * 16;
      int row = tb >> 7, gd = (tb >> 4) & 7;
      asrcF[j] = (const float*)Ap + (size_t)(tileM + row) * K + ((gd ^ (row & 7)) << 2);
      adstF[j] = Asf + w * 256 + j * 1024;
    }
  } else {
#pragma unroll
    for (int j = 0; j < 2; ++j) {
      int tb = w * 1024 + j * 4096 + (t & 63) * 16;
      int row = tb >> 6, gd = (tb >> 4) & 3;
      asrcH[j] = (const u16*)Ap + (size_t)(tileM + row) * K + ((gd ^ ((row >> 1) & 3)) << 3);
      adstH[j] = As16 + w * 512 + j * 2048;
    }
  }

  f32x4 acc[4][4];
#pragma unroll
  for (int m = 0; m < 4; ++m)
#pragma unroll
    for (int n = 0; n < 4; ++n) {
      f32x4 z = {0.f, 0.f, 0.f, 0.f};
      acc[m][n] = z;
    }

  for (int k0 = 0; k0 < K; k0 += 32) {
#pragma unroll
    for (int j = 0; j < 2; ++j) { gl16(bsrc[j], bdst[j]); bsrc[j] += 32; }
    if constexpr (AF32) {
#pragma unroll
      for (int j = 0; j < 4; ++j) { gl16(asrcF[j], adstF[j]); asrcF[j] += 32; }
    } else {
#pragma unroll
      for (int j = 0; j < 2; ++j) { gl16(asrcH[j], adstH[j]); asrcH[j] += 32; }
    }
    __syncthreads();

    bf16x8 av[4], bv[4];
#pragma unroll
    for (int m = 0; m < 4; ++m) {
      const int row = wr + m * 16 + fr;
      if constexpr (AF32) {
        const int g0 = (2 * fg) ^ (row & 7);
        const int g1 = (2 * fg + 1) ^ (row & 7);
        float4 p0 = *(const float4*)(Asf + row * 32 + g0 * 4);
        float4 p1 = *(const float4*)(Asf + row * 32 + g1 * 4);
        uint4 u;
        u.x = cvtpk(p0.x, p0.y); u.y = cvtpk(p0.z, p0.w);
        u.z = cvtpk(p1.x, p1.y); u.w = cvtpk(p1.z, p1.w);
        av[m] = __builtin_bit_cast(bf16x8, u);
      } else {
        const int g = fg ^ ((row >> 1) & 3);
        av[m] = __builtin_bit_cast(bf16x8, *(const u16x8*)(As16 + row * 32 + g * 8));
      }
    }
#pragma unroll
    for (int n = 0; n < 4; ++n) {
      const int row = wc + n * 16 + fr;
      const int g = fg ^ ((row >> 1) & 3);
      bv[n] = __builtin_bit_cast(bf16x8, *(const u16x8*)(Bs + row * 32 + g * 8));
    }
#pragma unroll
    for (int m = 0; m < 4; ++m)
#pragma unroll
      for (int n = 0; n < 4; ++n)
        acc[m][n] = mfma16(av[m], bv[n], acc[m][n]);
    __syncthreads();
  }

#pragma unroll
  for (int m = 0; m < 4; ++m) {
#pragma unroll
    for (int n = 0; n < 4; ++n) {
      const int gcol = tileN + wc + n * 16 + fr;
      const int growb = tileM + wr + m * 16 + fg * 4;
#pragma unroll
      for (int r = 0; r < 4; ++r) {
        const int grow = growb + r;
        float v = acc[m][n][r];
        if constexpr (EPI == EPI_GATES) {
          v += bias[gcol];   // b_ih + b_hh folded; coalesced plain layout (R9)
          ((u16*)Cp)[(size_t)grow * ldc + gcol] = f2b(v);
        } else if constexpr (EPI == EPI_H1) {
          v += bias[(grow >> 7) * 256 + gcol];
          v = fmaxf(v, 0.f);
          ((u16*)Cp)[(size_t)grow * ldc + gcol] = f2b(v);
        } else if constexpr (EPI == EPI_H2) {
          v += bias[gcol];
          v = fmaxf(v, 0.f);
          ((u16*)Cp)[(size_t)grow * ldc + gcol] = f2b(v);
        } else {
          v += bias[gcol];
          ((float*)Cp)[(size_t)grow * ldc + gcol] = sigf(v);
        }
      }
    }
  }
}

// ---------------- MFMA LSTM scan ----------------
// 16 blocks x 16 batches, 448 threads (7 waves). W_hh register-resident as
// 56 bf16x8 A-frags/lane (AGPR-eligible; proven no-spill in R10). Per step:
// 8 coalesced-ish uint2 gx loads (4 consecutive gate cols each) prefetched
// 2 steps ahead via parity-owned register sets; raw lgkmcnt-barrier keeps
// global loads in flight across the barrier (no vmcnt(0) drain).
__global__ __launch_bounds__(448) void lstm_scan(
    const u16* __restrict__ gates,    // [b*128+t][896] bf16 (plain, from GEMM)
    const uint4* __restrict__ Wf,     // frag-packed W_hh
    float* __restrict__ h_final) {    // [256][200]
  __shared__ __attribute__((aligned(16))) uint4 hbuf[2][7][64];
  const int tid = threadIdx.x;
  const int l = tid & 63;
  const int w = tid >> 6;
  const int fg = l >> 4;
  const int fr = l & 15;
  const int bglob = blockIdx.x * 16 + fr;

  // load W frags (coalesced, once)
  bf16x8 wf[8][7];
  {
    const uint4* wp = Wf + (size_t)w * 56 * 64 + l;
#pragma unroll
    for (int tt = 0; tt < 8; ++tt)
#pragma unroll
      for (int f = 0; f < 7; ++f)
        wf[tt][f] = __builtin_bit_cast(bf16x8, wp[(tt * 7 + f) * 64]);
  }
  for (int i = tid; i < 7 * 64; i += 448) {
    uint4 z = {0, 0, 0, 0};
    hbuf[0][i >> 6][i & 63] = z;
  }
  float c[8];
#pragma unroll
  for (int i = 0; i < 8; ++i) c[i] = 0.f;
  float hfin[8];

  // gate-x base for this lane's batch; col(tt) = (tt>>1)*200 + w*32 + (tt&1)*16 + fg*4
  // (for pad units u>=200 this reads into the next gate's region -> harmless,
  //  those lanes have zero W-frags and masked h-writes)
  const u16* grow0 = gates + (size_t)bglob * TLEN * LDG + w * 32 + fg * 4;
#define GXCOL(tt) ((tt >> 1) * 200 + ((tt) & 1) * 16)
  uint2 gxA[8], gxB[8];
#pragma unroll
  for (int tt = 0; tt < 8; ++tt) gxA[tt] = *(const uint2*)(grow0 + GXCOL(tt));
#pragma unroll
  for (int tt = 0; tt < 8; ++tt) gxB[tt] = *(const uint2*)(grow0 + LDG + GXCOL(tt));
  __syncthreads();

  auto step = [&](int tcur, uint2 (&gxc)[8], int parity) {
    // consume gx, then immediately re-issue loads for tcur+2 into same regs
    f32x4 acc[8];
#pragma unroll
    for (int tt = 0; tt < 8; ++tt) acc[tt] = gx4(gxc[tt]);
    if (tcur + 2 < TLEN) {
      const u16* gp = grow0 + (size_t)(tcur + 2) * LDG;
#pragma unroll
      for (int tt = 0; tt < 8; ++tt) gxc[tt] = *(const uint2*)(gp + GXCOL(tt));
    }
    // h frags
    bf16x8 hf[7];
#pragma unroll
    for (int f = 0; f < 7; ++f)
      hf[f] = __builtin_bit_cast(bf16x8, hbuf[parity][f][l]);
#pragma unroll
    for (int f = 0; f < 7; ++f)
#pragma unroll
      for (int tt = 0; tt < 8; ++tt)
        acc[tt] = mfma16(wf[tt][f], hf[f], acc[tt]);
    // activation (lane-local) + write h(t+1) frags
    const int nxt = parity ^ 1;
#pragma unroll
    for (int s = 0; s < 2; ++s) {
      float hh[4];
#pragma unroll
      for (int reg = 0; reg < 4; ++reg) {
        float gi = acc[0 + s][reg], gf = acc[2 + s][reg];
        float gg = acc[4 + s][reg], go = acc[6 + s][reg];
        int ci = s * 4 + reg;
        c[ci] = sigf(gf) * c[ci] + sigf(gi) * tanh_fast(gg);
        float h = sigf(go) * tanh_fast(c[ci]);
        int u = w * 32 + s * 16 + fg * 4 + reg;
        hh[reg] = (u < HID) ? h : 0.f;
        hfin[ci] = hh[reg];
      }
      uint2 pk;
      pk.x = cvtpk(hh[0], hh[1]);
      pk.y = cvtpk(hh[2], hh[3]);
      const int g = s * 2 + (fg >> 1);
      *(uint2*)((char*)&hbuf[nxt][w][0] + (g * 16 + fr) * 16 + (fg & 1) * 8) = pk;
    }
    // LDS writes drained; global prefetch stays in flight across the barrier
    asm volatile("s_waitcnt lgkmcnt(0)\n\ts_barrier" ::: "memory");
  };

  for (int t = 0; t < TLEN; t += 2) {
    step(t, gxA, 0);
    step(t + 1, gxB, 1);
  }

#pragma unroll
  for (int s = 0; s < 2; ++s)
#pragma unroll
    for (int reg = 0; reg < 4; ++reg) {
      int u = w * 32 + s * 16 + fg * 4 + reg;
      if (u < HID) h_final[(size_t)bglob * HID + u] = hfin[s * 4 + reg];
    }
#undef GXCOL
}

// ---------------- encoder + VQ + p1 (one block per batch) ----------------
__global__ __launch_bounds__(256) void enc_vq(
    const float* __restrict__ h_final,
    const float* __restrict__ Wenc, const float* __restrict__ b_enc,
    const float* __restrict__ emb, const float* __restrict__ W1,
    const float* __restrict__ b1, const float* __restrict__ noise,
    float* __restrict__ p1) {
  __shared__ __attribute__((aligned(16))) float sh_hf[HID];
  __shared__ __attribute__((aligned(16))) float sh_ze[LATENT];
  __shared__ float sh_zq[LATENT];
  __shared__ float sh_rd[256];
  __shared__ int sh_ri[256];
  const int r = threadIdx.x;
  const int b = blockIdx.x;

  if (r < HID) sh_hf[r] = h_final[(size_t)b * HID + r];
  __syncthreads();

  if (r < LATENT) {
    float z = b_enc[r];
#pragma unroll 4
    for (int k = 0; k < HID; ++k) z = fmaf(Wenc[(size_t)r * HID + k], sh_hf[k], z);
    sh_ze[r] = z;
  }
  __syncthreads();

  float best = INFINITY; int bi = 0;
  for (int k = r; k < NCODES; k += 256) {
    float d = 0.f;
#pragma unroll
    for (int q = 0; q < LATENT / 4; ++q) {
      float4 e = *(const float4*)&emb[(size_t)k * LATENT + q * 4];
      float4 z = *(const float4*)&sh_ze[q * 4];
      d += e.x * (e.x - 2.f * z.x) + e.y * (e.y - 2.f * z.y)
         + e.z * (e.z - 2.f * z.z) + e.w * (e.w - 2.f * z.w);
    }
    if (d < best) { best = d; bi = k; }
  }
  sh_rd[r] = best; sh_ri[r] = bi;
  __syncthreads();
  for (int s = 128; s > 0; s >>= 1) {
    if (r < s) {
      float od = sh_rd[r + s]; int oi = sh_ri[r + s];
      if (od < sh_rd[r] || (od == sh_rd[r] && oi < sh_ri[r])) { sh_rd[r] = od; sh_ri[r] = oi; }
    }
    __syncthreads();
  }
  const int kmin = sh_ri[0];
  if (r < LATENT) sh_zq[r] = emb[(size_t)kmin * LATENT + r];
  __syncthreads();

  // p1[b][j] = b1 + W1[:,0:128].zq + W1[:,1664:2432].noise (pad 200..255 = 0)
  float v = 0.f;
  if (r < HID) {
    v = b1[r];
    const float* wrow = W1 + (size_t)r * 2432;
#pragma unroll 4
    for (int d = 0; d < LATENT; ++d) v = fmaf(wrow[d], sh_zq[d], v);
    const float* nz = noise + (size_t)b * DIN;
#pragma unroll 4
    for (int d = 0; d < DIN; ++d) v = fmaf(wrow[1664 + d], nz[d], v);
  }
  p1[b * 256 + r] = v;
}

// ---------------- host ----------------
extern "C" void kernel_launch(void* const* d_in, const int* in_sizes, int n_in,
                              void* d_out, int out_size, void* d_ws, size_t ws_size,
                              hipStream_t stream) {
  const float* x     = (const float*)d_in[0];
  const float* cond  = (const float*)d_in[1];
  const float* noise = (const float*)d_in[2];
  const float* W_ih  = (const float*)d_in[3];
  const float* W_hh  = (const float*)d_in[4];
  const float* b_ih  = (const float*)d_in[5];
  const float* b_hh  = (const float*)d_in[6];
  const float* W_enc = (const float*)d_in[7];
  const float* b_enc = (const float*)d_in[8];
  const float* emb   = (const float*)d_in[9];
  const float* W1    = (const float*)d_in[10];
  const float* b1    = (const float*)d_in[11];
  const float* W2    = (const float*)d_in[12];
  const float* b2    = (const float*)d_in[13];
  const float* W3    = (const float*)d_in[14];
  const float* b3    = (const float*)d_in[15];

  char* ws = (char*)d_ws;
  size_t off = 0;
  auto alloc = [&](size_t bytes) -> void* {
    void* p = ws + off; off += (bytes + 255) & ~(size_t)255; return p;
  };
  u16*   W_ihb = (u16*)alloc((size_t)896 * 768 * 2);
  u16*   W1cb  = (u16*)alloc((size_t)256 * 1536 * 2);
  u16*   W2b   = (u16*)alloc((size_t)512 * 256 * 2);
  u16*   W3b   = (u16*)alloc((size_t)768 * 512 * 2);
  float* b2p   = (float*)alloc(512 * 4);
  uint4* Wf    = (uint4*)alloc((size_t)56 * 64 * 16);
  float* biasc = (float*)alloc(LDG * 4);
  u16*   gates = (u16*)alloc((size_t)MROWS * LDG * 2);   // [b*128+t][896]
  float* h_fin = (float*)alloc((size_t)NB * HID * 4);
  float* p1    = (float*)alloc(256 * 256 * 4);
  u16*   h1    = (u16*)alloc((size_t)MROWS * LDH1 * 2);
  u16*   h2    = (u16*)alloc((size_t)MROWS * LDH2 * 2);

  cvt_pad<<<dim3((896 * 768 + 255) / 256), 256, 0, stream>>>(W_ih, W_ihb, 800, 768, 768, 0, 896, 768);
  cvt_pad<<<dim3((256 * 1536 + 255) / 256), 256, 0, stream>>>(W1, W1cb, 200, 1536, 2432, 128, 256, 1536);
  cvt_pad<<<dim3((512 * 256 + 255) / 256), 256, 0, stream>>>(W2, W2b, 400, 200, 200, 0, 512, 256);
  cvt_pad<<<dim3((768 * 512 + 255) / 256), 256, 0, stream>>>(W3, W3b, 768, 400, 400, 0, 768, 512);
  pad_f32<<<dim3(2), 256, 0, stream>>>(b2, b2p, 400, 512);
  bias_pack<<<dim3(4), 256, 0, stream>>>(b_ih, b_hh, biasc);
  pack_wf<<<dim3(14), 256, 0, stream>>>(W_hh, Wf);

  // gates = x @ W_ih^T + (b_ih+b_hh), plain coalesced [row][896]
  gemm_bf16<true, EPI_GATES><<<dim3(LDG / 128, MROWS / 128), 256, 0, stream>>>(
      x, W_ihb, gates, 768, LDG, biasc);

  // MFMA LSTM scan (16 blocks x 16 batches)
  lstm_scan<<<dim3(16), 448, 0, stream>>>(gates, Wf, h_fin);

  // encoder + VQ + p1
  enc_vq<<<dim3(NB), 256, 0, stream>>>(h_fin, W_enc, b_enc, emb, W1, b1, noise, p1);

  // h1 = relu(cond @ W1c^T + p1[b])
  gemm_bf16<true, EPI_H1><<<dim3(LDH1 / 128, MROWS / 128), 256, 0, stream>>>(
      cond, W1cb, h1, DCOND, LDH1, p1);
  // h2 = relu(h1 @ W2^T + b2)
  gemm_bf16<false, EPI_H2><<<dim3(LDH2 / 128, MROWS / 128), 256, 0, stream>>>(
      h1, W2b, h2, LDH1, LDH2, b2p);
  // out = sigmoid(h2 @ W3^T + b3)
  gemm_bf16<false, EPI_OUT><<<dim3(NOUT / 128, MROWS / 128), 256, 0, stream>>>(
      h2, W3b, (float*)d_out, LDH2, NOUT, b3);
}

// Round 12
// 1045.799 us; speedup vs baseline: 1.2146x; 1.2146x over previous
//
#include <hip/hip_runtime.h>
#include <math.h>

typedef unsigned short u16;
typedef u16 u16x8 __attribute__((ext_vector_type(8)));
typedef __bf16 bf16x8 __attribute__((ext_vector_type(8)));
typedef float f32x4 __attribute__((ext_vector_type(4)));

#define HID 200
#define G4H 800
#define TLEN 128
#define LATENT 128
#define NCODES 1024
#define DIN 768
#define DCOND 1536
#define NB 256
#define MROWS (NB * TLEN)
#define LDG 896
#define LDH1 256
#define LDH2 512
#define NOUT 768
#define ROWB (LDG * 2)          // 1792 bytes per gates row
#define TILEB (16 * ROWB)       // 28672 bytes staged per step

__device__ __forceinline__ u16 f2b(float f) {
  union { float f; unsigned u; } v; v.f = f;
  unsigned r = v.u + 0x7fffu + ((v.u >> 16) & 1u);
  return (u16)(r >> 16);
}
__device__ __forceinline__ float b2f(u16 h) {
  union { unsigned u; float f; } v; v.u = ((unsigned)h) << 16;
  return v.f;
}
__device__ __forceinline__ float sigf(float x) { return 1.f / (1.f + __expf(-x)); }
__device__ __forceinline__ float tanh_fast(float x) {
  return 1.f - 2.f / (__expf(2.f * x) + 1.f);
}

// async global->LDS, 16B per lane; LDS dest = wave-uniform base (+lane*16 by HW)
__device__ __forceinline__ void gl16(const void* g, void* l) {
  __builtin_amdgcn_global_load_lds(
      (const __attribute__((address_space(1))) void*)g,
      (__attribute__((address_space(3))) void*)l, 16, 0, 0);
}

__device__ __forceinline__ unsigned cvtpk(float a, float b) {
  unsigned r;
  asm("v_cvt_pk_bf16_f32 %0, %1, %2" : "=v"(r) : "v"(a), "v"(b));
  return r;
}

// unpack 4 bf16 (as uint2) -> f32x4
__device__ __forceinline__ f32x4 gx4(uint2 u) {
  union { unsigned q; float f; } a;
  f32x4 r;
  a.q = u.x << 16;          r.x = a.f;
  a.q = u.x & 0xFFFF0000u;  r.y = a.f;
  a.q = u.y << 16;          r.z = a.f;
  a.q = u.y & 0xFFFF0000u;  r.w = a.f;
  return r;
}

// ---------------- weight convert + pad ----------------
__global__ void cvt_pad(const float* __restrict__ src, u16* __restrict__ dst,
                        int nr, int nc, int lds, int col0, int NRp, int KP) {
  int i = blockIdx.x * blockDim.x + threadIdx.x;
  if (i >= NRp * KP) return;
  int r = i / KP, c = i - r * KP;
  float v = (r < nr && c < nc) ? src[(size_t)r * lds + col0 + c] : 0.f;
  dst[i] = f2b(v);
}

__global__ void pad_f32(const float* __restrict__ src, float* __restrict__ dst,
                        int n, int npad) {
  int i = blockIdx.x * blockDim.x + threadIdx.x;
  if (i < npad) dst[i] = (i < n) ? src[i] : 0.f;
}

// biasc[col<896] = b_ih + b_hh (0-padded)
__global__ void bias_pack(const float* __restrict__ b_ih, const float* __restrict__ b_hh,
                          float* __restrict__ biasc) {
  int i = blockIdx.x * blockDim.x + threadIdx.x;
  if (i < LDG) biasc[i] = (i < G4H) ? (b_ih[i] + b_hh[i]) : 0.f;
}

// W_hh [800][200] f32 -> MFMA A-fragments, bf16.
// Wf[((w*8+tt)*7+f)*64 + l]: tile tt: gate=tt>>1, s=tt&1; row u=w*32+s*16+(l&15)
// (pad u>=200 -> 0); k = f*32 + (l>>4)*8 + 2d+{0,1} (pad k>=200 -> 0).
__global__ void pack_wf(const float* __restrict__ Whh, uint4* __restrict__ Wf) {
  int i = blockIdx.x * blockDim.x + threadIdx.x;
  if (i >= 56 * 64) return;
  int l = i & 63, rest = i >> 6;
  int f = rest % 7, tt = (rest / 7) & 7, w = rest / 56;
  int gate = tt >> 1, s = tt & 1;
  int u = w * 32 + s * 16 + (l & 15);
  int kbase = f * 32 + (l >> 4) * 8;
  unsigned out[4];
#pragma unroll
  for (int d = 0; d < 4; ++d) {
    unsigned lo = 0, hi = 0;
    int k0 = kbase + 2 * d, k1 = k0 + 1;
    if (u < HID) {
      const float* row = Whh + (size_t)(gate * HID + u) * HID;
      if (k0 < HID) lo = f2b(row[k0]);
      if (k1 < HID) hi = f2b(row[k1]);
    }
    out[d] = lo | (hi << 16);
  }
  uint4 o; o.x = out[0]; o.y = out[1]; o.z = out[2]; o.w = out[3];
  Wf[i] = o;
}

// ---------------- bf16 MFMA GEMM: C[M,N] = A[M,K] * B[N,K]^T (+epilogue) ----------------
enum { EPI_GATES = 0, EPI_H1 = 1, EPI_H2 = 2, EPI_OUT = 3 };

__device__ __forceinline__ f32x4 mfma16(bf16x8 a, bf16x8 b, f32x4 c) {
  return __builtin_amdgcn_mfma_f32_16x16x32_bf16(a, b, c, 0, 0, 0);
}

template<bool AF32, int EPI>
__global__ __launch_bounds__(256) void gemm_bf16(
    const void* __restrict__ Ap, const u16* __restrict__ Bp,
    void* __restrict__ Cp, int K, int ldc, const float* __restrict__ bias) {
  __shared__ __attribute__((aligned(16))) char AsRaw[AF32 ? 128 * 32 * 4 : 128 * 32 * 2];
  __shared__ __attribute__((aligned(16))) u16 Bs[128 * 32];
  float* Asf = (float*)AsRaw;
  u16* As16 = (u16*)AsRaw;

  const int t = threadIdx.x;
  const int tileN = blockIdx.x * 128;
  const int tileM = blockIdx.y * 128;
  const int l = t & 63;
  const int w = t >> 6;
  const int wr = (w >> 1) * 64;
  const int wc = (w & 1) * 64;
  const int fr = l & 15;
  const int fg = l >> 4;

  const u16* bsrc[2];
  u16* bdst[2];
#pragma unroll
  for (int j = 0; j < 2; ++j) {
    int tb = w * 1024 + j * 4096 + (t & 63) * 16;
    int row = tb >> 6, gd = (tb >> 4) & 3;
    bsrc[j] = Bp + (size_t)(tileN + row) * K + ((gd ^ ((row >> 1) & 3)) << 3);
    bdst[j] = Bs + w * 512 + j * 2048;
  }
  const float* asrcF[4];
  float* adstF[4];
  const u16* asrcH[2];
  u16* adstH[2];
  if constexpr (AF32) {
#pragma unroll
    for (int j = 0; j < 4; ++j) {
      int tb = w * 1024 + j * 4096 + (t & 63) * 16;
      int row = tb >> 7, gd = (tb >> 4) & 7;
      asrcF[j] = (const float*)Ap + (size_t)(tileM + row) * K + ((gd ^ (row & 7)) << 2);
      adstF[j] = Asf + w * 256 + j * 1024;
    }
  } else {
#pragma unroll
    for (int j = 0; j < 2; ++j) {
      int tb = w * 1024 + j * 4096 + (t & 63) * 16;
      int row = tb >> 6, gd = (tb >> 4) & 3;
      asrcH[j] = (const u16*)Ap + (size_t)(tileM + row) * K + ((gd ^ ((row >> 1) & 3)) << 3);
      adstH[j] = As16 + w * 512 + j * 2048;
    }
  }

  f32x4 acc[4][4];
#pragma unroll
  for (int m = 0; m < 4; ++m)
#pragma unroll
    for (int n = 0; n < 4; ++n) {
      f32x4 z = {0.f, 0.f, 0.f, 0.f};
      acc[m][n] = z;
    }

  for (int k0 = 0; k0 < K; k0 += 32) {
#pragma unroll
    for (int j = 0; j < 2; ++j) { gl16(bsrc[j], bdst[j]); bsrc[j] += 32; }
    if constexpr (AF32) {
#pragma unroll
      for (int j = 0; j < 4; ++j) { gl16(asrcF[j], adstF[j]); asrcF[j] += 32; }
    } else {
#pragma unroll
      for (int j = 0; j < 2; ++j) { gl16(asrcH[j], adstH[j]); asrcH[j] += 32; }
    }
    __syncthreads();

    bf16x8 av[4], bv[4];
#pragma unroll
    for (int m = 0; m < 4; ++m) {
      const int row = wr + m * 16 + fr;
      if constexpr (AF32) {
        const int g0 = (2 * fg) ^ (row & 7);
        const int g1 = (2 * fg + 1) ^ (row & 7);
        float4 p0 = *(const float4*)(Asf + row * 32 + g0 * 4);
        float4 p1 = *(const float4*)(Asf + row * 32 + g1 * 4);
        uint4 u;
        u.x = cvtpk(p0.x, p0.y); u.y = cvtpk(p0.z, p0.w);
        u.z = cvtpk(p1.x, p1.y); u.w = cvtpk(p1.z, p1.w);
        av[m] = __builtin_bit_cast(bf16x8, u);
      } else {
        const int g = fg ^ ((row >> 1) & 3);
        av[m] = __builtin_bit_cast(bf16x8, *(const u16x8*)(As16 + row * 32 + g * 8));
      }
    }
#pragma unroll
    for (int n = 0; n < 4; ++n) {
      const int row = wc + n * 16 + fr;
      const int g = fg ^ ((row >> 1) & 3);
      bv[n] = __builtin_bit_cast(bf16x8, *(const u16x8*)(Bs + row * 32 + g * 8));
    }
#pragma unroll
    for (int m = 0; m < 4; ++m)
#pragma unroll
      for (int n = 0; n < 4; ++n)
        acc[m][n] = mfma16(av[m], bv[n], acc[m][n]);
    __syncthreads();
  }

#pragma unroll
  for (int m = 0; m < 4; ++m) {
#pragma unroll
    for (int n = 0; n < 4; ++n) {
      const int gcol = tileN + wc + n * 16 + fr;
      const int growb = tileM + wr + m * 16 + fg * 4;
#pragma unroll
      for (int r = 0; r < 4; ++r) {
        const int grow = growb + r;
        float v = acc[m][n][r];
        if constexpr (EPI == EPI_GATES) {
          v += bias[gcol];   // b_ih + b_hh folded; coalesced plain layout
          ((u16*)Cp)[(size_t)grow * ldc + gcol] = f2b(v);
        } else if constexpr (EPI == EPI_H1) {
          v += bias[(grow >> 7) * 256 + gcol];
          v = fmaxf(v, 0.f);
          ((u16*)Cp)[(size_t)grow * ldc + gcol] = f2b(v);
        } else if constexpr (EPI == EPI_H2) {
          v += bias[gcol];
          v = fmaxf(v, 0.f);
          ((u16*)Cp)[(size_t)grow * ldc + gcol] = f2b(v);
        } else {
          v += bias[gcol];
          ((float*)Cp)[(size_t)grow * ldc + gcol] = sigf(v);
        }
      }
    }
  }
}

// ---------------- MFMA LSTM scan ----------------
// 16 blocks x 16 batches, 448 threads (7 waves). W_hh register-resident as
// 56 bf16x8 A-frags/lane. Gates staged per-step through LDS via global_load_lds
// (per-lane GLOBAL source = coalesced reads of 16 batch rows; linear LDS dest;
// rule-21 XOR swizzle on source + read to kill the 16-way stride-1792 conflict).
// Double-buffered 2x28KB; end-of-step vmcnt(0)+lgkmcnt(0)+s_barrier: stage(t+1)
// issued a full step earlier, so HBM/L2 latency hides under MFMA+activation.
__global__ __launch_bounds__(448) void lstm_scan(
    const u16* __restrict__ gates,    // [b*128+t][896] bf16 (plain, from GEMM)
    const uint4* __restrict__ Wf,     // frag-packed W_hh
    float* __restrict__ h_final) {    // [256][200]
  __shared__ __attribute__((aligned(16))) char gbuf[2][TILEB];
  __shared__ __attribute__((aligned(16))) uint4 hbuf[2][7][64];
  const int tid = threadIdx.x;
  const int l = tid & 63;
  const int w = tid >> 6;
  const int fg = l >> 4;
  const int fr = l & 15;
  const int bglob = blockIdx.x * 16 + fr;

  // load W frags (coalesced, once)
  bf16x8 wf[8][7];
  {
    const uint4* wp = Wf + (size_t)w * 56 * 64 + l;
#pragma unroll
    for (int tt = 0; tt < 8; ++tt)
#pragma unroll
      for (int f = 0; f < 7; ++f)
        wf[tt][f] = __builtin_bit_cast(bf16x8, wp[(tt * 7 + f) * 64]);
  }
  for (int i = tid; i < 7 * 64; i += 448) {
    uint4 z = {0, 0, 0, 0};
    hbuf[0][i >> 6][i & 63] = z;
  }

  // staging: 4 x 16B per thread per step. off = j*7168 + w*1024 + l*16;
  // row = off/1792 (batch within tile), colb = off%1792; source granule
  // pre-swizzled: colb ^ ((row&7)<<4). Dest passed wave-uniform (HW adds lane*16).
  const char* gsrc[4];
  unsigned gdst[4];
#pragma unroll
  for (int j = 0; j < 4; ++j) {
    int off = j * 7168 + w * 1024 + l * 16;
    int row = off / ROWB, colb = off % ROWB;
    int swc = colb ^ ((row & 7) << 4);
    gsrc[j] = (const char*)gates + ((size_t)(blockIdx.x * 16 + row) * TLEN) * ROWB + swc;
    gdst[j] = j * 7168 + w * 1024;   // wave-uniform LDS byte offset
  }
  // gx LDS read offsets (same XOR on read side; involution)
  int gxoff[8];
#pragma unroll
  for (int tt = 0; tt < 8; ++tt) {
    int col = (tt >> 1) * 200 + (tt & 1) * 16 + w * 32 + fg * 4;
    int colb = col * 2;
    gxoff[tt] = fr * ROWB + (colb ^ ((fr & 7) << 4));
  }

  // prologue: stage t=0 into gbuf[0]
#pragma unroll
  for (int j = 0; j < 4; ++j) gl16(gsrc[j], (char*)gbuf[0] + gdst[j]);
  __syncthreads();   // full drain: buf0 resident

  float c[8];
#pragma unroll
  for (int i = 0; i < 8; ++i) c[i] = 0.f;
  float hfin[8];

  for (int t = 0; t < TLEN; ++t) {
    const int cur = t & 1, nxt = cur ^ 1;
    // issue stage for t+1 (stays in flight through this step's compute)
    if (t + 1 < TLEN) {
      const size_t tb = (size_t)(t + 1) * ROWB;
#pragma unroll
      for (int j = 0; j < 4; ++j) gl16(gsrc[j] + tb, (char*)gbuf[nxt] + gdst[j]);
    }
    // gx from staged LDS (swizzled b64 reads)
    f32x4 acc[8];
#pragma unroll
    for (int tt = 0; tt < 8; ++tt) {
      uint2 g = *(const uint2*)(gbuf[cur] + gxoff[tt]);
      acc[tt] = gx4(g);
    }
    // h frags
    bf16x8 hf[7];
#pragma unroll
    for (int f = 0; f < 7; ++f)
      hf[f] = __builtin_bit_cast(bf16x8, hbuf[cur][f][l]);
#pragma unroll
    for (int f = 0; f < 7; ++f)
#pragma unroll
      for (int tt = 0; tt < 8; ++tt)
        acc[tt] = mfma16(wf[tt][f], hf[f], acc[tt]);
    // activation (lane-local) + write h(t+1) frags
#pragma unroll
    for (int s = 0; s < 2; ++s) {
      float hh[4];
#pragma unroll
      for (int reg = 0; reg < 4; ++reg) {
        float gi = acc[0 + s][reg], gf = acc[2 + s][reg];
        float gg = acc[4 + s][reg], go = acc[6 + s][reg];
        int ci = s * 4 + reg;
        c[ci] = sigf(gf) * c[ci] + sigf(gi) * tanh_fast(gg);
        float h = sigf(go) * tanh_fast(c[ci]);
        int u = w * 32 + s * 16 + fg * 4 + reg;
        hh[reg] = (u < HID) ? h : 0.f;
        hfin[ci] = hh[reg];
      }
      uint2 pk;
      pk.x = cvtpk(hh[0], hh[1]);
      pk.y = cvtpk(hh[2], hh[3]);
      const int g = s * 2 + (fg >> 1);
      *(uint2*)((char*)&hbuf[nxt][w][0] + (g * 16 + fr) * 16 + (fg & 1) * 8) = pk;
    }
    // stage(t+1) complete + LDS writes visible before next step
    asm volatile("s_waitcnt vmcnt(0) lgkmcnt(0)\n\ts_barrier" ::: "memory");
  }

#pragma unroll
  for (int s = 0; s < 2; ++s)
#pragma unroll
    for (int reg = 0; reg < 4; ++reg) {
      int u = w * 32 + s * 16 + fg * 4 + reg;
      if (u < HID) h_final[(size_t)bglob * HID + u] = hfin[s * 4 + reg];
    }
}

// ---------------- encoder + VQ + p1 (one block per batch) ----------------
__global__ __launch_bounds__(256) void enc_vq(
    const float* __restrict__ h_final,
    const float* __restrict__ Wenc, const float* __restrict__ b_enc,
    const float* __restrict__ emb, const float* __restrict__ W1,
    const float* __restrict__ b1, const float* __restrict__ noise,
    float* __restrict__ p1) {
  __shared__ __attribute__((aligned(16))) float sh_hf[HID];
  __shared__ __attribute__((aligned(16))) float sh_ze[LATENT];
  __shared__ float sh_zq[LATENT];
  __shared__ float sh_rd[256];
  __shared__ int sh_ri[256];
  const int r = threadIdx.x;
  const int b = blockIdx.x;

  if (r < HID) sh_hf[r] = h_final[(size_t)b * HID + r];
  __syncthreads();

  if (r < LATENT) {
    float z = b_enc[r];
#pragma unroll 4
    for (int k = 0; k < HID; ++k) z = fmaf(Wenc[(size_t)r * HID + k], sh_hf[k], z);
    sh_ze[r] = z;
  }
  __syncthreads();

  float best = INFINITY; int bi = 0;
  for (int k = r; k < NCODES; k += 256) {
    float d = 0.f;
#pragma unroll
    for (int q = 0; q < LATENT / 4; ++q) {
      float4 e = *(const float4*)&emb[(size_t)k * LATENT + q * 4];
      float4 z = *(const float4*)&sh_ze[q * 4];
      d += e.x * (e.x - 2.f * z.x) + e.y * (e.y - 2.f * z.y)
         + e.z * (e.z - 2.f * z.z) + e.w * (e.w - 2.f * z.w);
    }
    if (d < best) { best = d; bi = k; }
  }
  sh_rd[r] = best; sh_ri[r] = bi;
  __syncthreads();
  for (int s = 128; s > 0; s >>= 1) {
    if (r < s) {
      float od = sh_rd[r + s]; int oi = sh_ri[r + s];
      if (od < sh_rd[r] || (od == sh_rd[r] && oi < sh_ri[r])) { sh_rd[r] = od; sh_ri[r] = oi; }
    }
    __syncthreads();
  }
  const int kmin = sh_ri[0];
  if (r < LATENT) sh_zq[r] = emb[(size_t)kmin * LATENT + r];
  __syncthreads();

  // p1[b][j] = b1 + W1[:,0:128].zq + W1[:,1664:2432].noise (pad 200..255 = 0)
  float v = 0.f;
  if (r < HID) {
    v = b1[r];
    const float* wrow = W1 + (size_t)r * 2432;
#pragma unroll 4
    for (int d = 0; d < LATENT; ++d) v = fmaf(wrow[d], sh_zq[d], v);
    const float* nz = noise + (size_t)b * DIN;
#pragma unroll 4
    for (int d = 0; d < DIN; ++d) v = fmaf(wrow[1664 + d], nz[d], v);
  }
  p1[b * 256 + r] = v;
}

// ---------------- host ----------------
extern "C" void kernel_launch(void* const* d_in, const int* in_sizes, int n_in,
                              void* d_out, int out_size, void* d_ws, size_t ws_size,
                              hipStream_t stream) {
  const float* x     = (const float*)d_in[0];
  const float* cond  = (const float*)d_in[1];
  const float* noise = (const float*)d_in[2];
  const float* W_ih  = (const float*)d_in[3];
  const float* W_hh  = (const float*)d_in[4];
  const float* b_ih  = (const float*)d_in[5];
  const float* b_hh  = (const float*)d_in[6];
  const float* W_enc = (const float*)d_in[7];
  const float* b_enc = (const float*)d_in[8];
  const float* emb   = (const float*)d_in[9];
  const float* W1    = (const float*)d_in[10];
  const float* b1    = (const float*)d_in[11];
  const float* W2    = (const float*)d_in[12];
  const float* b2    = (const float*)d_in[13];
  const float* W3    = (const float*)d_in[14];
  const float* b3    = (const float*)d_in[15];

  char* ws = (char*)d_ws;
  size_t off = 0;
  auto alloc = [&](size_t bytes) -> void* {
    void* p = ws + off; off += (bytes + 255) & ~(size_t)255; return p;
  };
  u16*   W_ihb = (u16*)alloc((size_t)896 * 768 * 2);
  u16*   W1cb  = (u16*)alloc((size_t)256 * 1536 * 2);
  u16*   W2b   = (u16*)alloc((size_t)512 * 256 * 2);
  u16*   W3b   = (u16*)alloc((size_t)768 * 512 * 2);
  float* b2p   = (float*)alloc(512 * 4);
  uint4* Wf    = (uint4*)alloc((size_t)56 * 64 * 16);
  float* biasc = (float*)alloc(LDG * 4);
  u16*   gates = (u16*)alloc((size_t)MROWS * LDG * 2);   // [b*128+t][896]
  float* h_fin = (float*)alloc((size_t)NB * HID * 4);
  float* p1    = (float*)alloc(256 * 256 * 4);
  u16*   h1    = (u16*)alloc((size_t)MROWS * LDH1 * 2);
  u16*   h2    = (u16*)alloc((size_t)MROWS * LDH2 * 2);

  cvt_pad<<<dim3((896 * 768 + 255) / 256), 256, 0, stream>>>(W_ih, W_ihb, 800, 768, 768, 0, 896, 768);
  cvt_pad<<<dim3((256 * 1536 + 255) / 256), 256, 0, stream>>>(W1, W1cb, 200, 1536, 2432, 128, 256, 1536);
  cvt_pad<<<dim3((512 * 256 + 255) / 256), 256, 0, stream>>>(W2, W2b, 400, 200, 200, 0, 512, 256);
  cvt_pad<<<dim3((768 * 512 + 255) / 256), 256, 0, stream>>>(W3, W3b, 768, 400, 400, 0, 768, 512);
  pad_f32<<<dim3(2), 256, 0, stream>>>(b2, b2p, 400, 512);
  bias_pack<<<dim3(4), 256, 0, stream>>>(b_ih, b_hh, biasc);
  pack_wf<<<dim3(14), 256, 0, stream>>>(W_hh, Wf);

  // gates = x @ W_ih^T + (b_ih+b_hh), plain coalesced [row][896]
  gemm_bf16<true, EPI_GATES><<<dim3(LDG / 128, MROWS / 128), 256, 0, stream>>>(
      x, W_ihb, gates, 768, LDG, biasc);

  // MFMA LSTM scan (16 blocks x 16 batches, LDS-staged gates)
  lstm_scan<<<dim3(16), 448, 0, stream>>>(gates, Wf, h_fin);

  // encoder + VQ + p1
  enc_vq<<<dim3(NB), 256, 0, stream>>>(h_fin, W_enc, b_enc, emb, W1, b1, noise, p1);

  // h1 = relu(cond @ W1c^T + p1[b])
  gemm_bf16<true, EPI_H1><<<dim3(LDH1 / 128, MROWS / 128), 256, 0, stream>>>(
      cond, W1cb, h1, DCOND, LDH1, p1);
  // h2 = relu(h1 @ W2^T + b2)
  gemm_bf16<false, EPI_H2><<<dim3(LDH2 / 128, MROWS / 128), 256, 0, stream>>>(
      h1, W2b, h2, LDH1, LDH2, b2p);
  // out = sigmoid(h2 @ W3^T + b3)
  gemm_bf16<false, EPI_OUT><<<dim3(NOUT / 128, MROWS / 128), 256, 0, stream>>>(
      h2, W3b, (float*)d_out, LDH2, NOUT, b3);
}

// Round 13
// 624.568 us; speedup vs baseline: 2.0337x; 1.6744x over previous
//
#include <hip/hip_runtime.h>
#include <math.h>

typedef unsigned short u16;
typedef u16 u16x8 __attribute__((ext_vector_type(8)));
typedef __bf16 bf16x8 __attribute__((ext_vector_type(8)));
typedef float f32x4 __attribute__((ext_vector_type(4)));

#define HID 200
#define G4H 800
#define TLEN 128
#define LATENT 128
#define NCODES 1024
#define DIN 768
#define DCOND 1536
#define NB 256
#define MROWS (NB * TLEN)
#define LDG 896
#define LDH1 256
#define LDH2 512
#define NOUT 768

#define WSCL4 40.0f
#define HSCL 127.0f
#define ISCL4 (1.0f / (WSCL4 * HSCL))
#define W4_UINT4 (6 * 800)           // k 0..191, i4-packed, [jb][row] uint4
#define W4_BYTES (W4_UINT4 * 16)     // 76800

__device__ __forceinline__ u16 f2b(float f) {
  union { float f; unsigned u; } v; v.f = f;
  unsigned r = v.u + 0x7fffu + ((v.u >> 16) & 1u);
  return (u16)(r >> 16);
}
__device__ __forceinline__ float b2f(u16 h) {
  union { unsigned u; float f; } v; v.u = ((unsigned)h) << 16;
  return v.f;
}
__device__ __forceinline__ float sigf(float x) { return 1.f / (1.f + __expf(-x)); }
__device__ __forceinline__ float tanh_fast(float x) {
  return 1.f - 2.f / (__expf(2.f * x) + 1.f);
}

__device__ __forceinline__ int dot4(unsigned a, unsigned b, int c) {
#if __has_builtin(__builtin_amdgcn_sdot4)
  return __builtin_amdgcn_sdot4((int)a, (int)b, c, false);
#else
  int s = c;
  s += (int)(signed char)(a) * (int)(signed char)(b);
  s += (int)(signed char)(a >> 8) * (int)(signed char)(b >> 8);
  s += (int)(signed char)(a >> 16) * (int)(signed char)(b >> 16);
  s += (int)(signed char)(a >> 24) * (int)(signed char)(b >> 24);
  return s;
#endif
}

// i4x8 packed dword -> two i8x4 dwords (lo = nibbles j0..3, hi = j4..7);
// packing places j<4 in low nibbles of bytes 0..3, j>=4 in high nibbles.
__device__ __forceinline__ void unp4(unsigned d, unsigned& lo, unsigned& hi) {
  unsigned a = d & 0x0F0F0F0Fu;
  unsigned b = (d >> 4) & 0x0F0F0F0Fu;
  lo = (a ^ 0x08080808u) - 0x08080808u;
  hi = (b ^ 0x08080808u) - 0x08080808u;
}

// async global->LDS, 16B per lane
__device__ __forceinline__ void gl16(const void* g, void* l) {
  __builtin_amdgcn_global_load_lds(
      (const __attribute__((address_space(1))) void*)g,
      (__attribute__((address_space(3))) void*)l, 16, 0, 0);
}

__device__ __forceinline__ unsigned cvtpk(float a, float b) {
  unsigned r;
  asm("v_cvt_pk_bf16_f32 %0, %1, %2" : "=v"(r) : "v"(a), "v"(b));
  return r;
}

// ---------------- weight convert + pad ----------------
__global__ void cvt_pad(const float* __restrict__ src, u16* __restrict__ dst,
                        int nr, int nc, int lds, int col0, int NRp, int KP) {
  int i = blockIdx.x * blockDim.x + threadIdx.x;
  if (i >= NRp * KP) return;
  int r = i / KP, c = i - r * KP;
  float v = (r < nr && c < nc) ? src[(size_t)r * lds + col0 + c] : 0.f;
  dst[i] = f2b(v);
}

__global__ void pad_f32(const float* __restrict__ src, float* __restrict__ dst,
                        int n, int npad) {
  int i = blockIdx.x * blockDim.x + threadIdx.x;
  if (i < npad) dst[i] = (i < n) ? src[i] : 0.f;
}

// W_hh [800][200] f32 -> i4 (x40 scale), nibble-interleaved for cheap unpack:
//   k 0..191 -> W4u[((dw>>2)*800 + row)*4 + (dw&3)], dw = k/8
//   k 192..199 -> Wreg2[r] = {tail(row r), tail(row r+400)}
// biasc[col<896] = b_ih+b_hh (0-padded) for the gates-GEMM epilogue.
__global__ void pack_whh_i4(const float* __restrict__ Whh, unsigned* __restrict__ W4u,
                            unsigned* __restrict__ WregU,
                            const float* __restrict__ b_ih, const float* __restrict__ b_hh,
                            float* __restrict__ biasc) {
  int i = blockIdx.x * blockDim.x + threadIdx.x;
  if (i < 800 * 25) {
    int row = i / 25, dw = i - row * 25;
    unsigned d = 0;
#pragma unroll
    for (int j = 0; j < 8; ++j) {
      int k = dw * 8 + j;
      int q = (int)lrintf(Whh[(size_t)row * HID + k] * WSCL4);
      q = q > 7 ? 7 : (q < -8 ? -8 : q);
      d |= ((unsigned)(q & 0xF)) << (8 * (j & 3) + 4 * (j >> 2));
    }
    if (dw < 24) {
      W4u[(((dw >> 2) * 800 + row) << 2) | (dw & 3)] = d;
    } else {  // dw == 24: k 192..199
      if (row < 400) WregU[row * 2] = d;
      else WregU[(row - 400) * 2 + 1] = d;
    }
  }
  if (i < LDG) biasc[i] = (i < G4H) ? (b_ih[i] + b_hh[i]) : 0.f;
}

// ---------------- bf16 MFMA GEMM: C[M,N] = A[M,K] * B[N,K]^T (+epilogue) ----------------
enum { EPI_GATES = 0, EPI_H1 = 1, EPI_H2 = 2, EPI_OUT = 3 };

__device__ __forceinline__ f32x4 mfma16(bf16x8 a, bf16x8 b, f32x4 c) {
  return __builtin_amdgcn_mfma_f32_16x16x32_bf16(a, b, c, 0, 0, 0);
}

template<bool AF32, int EPI>
__global__ __launch_bounds__(256) void gemm_bf16(
    const void* __restrict__ Ap, const u16* __restrict__ Bp,
    void* __restrict__ Cp, int K, int ldc, const float* __restrict__ bias) {
  __shared__ __attribute__((aligned(16))) char AsRaw[AF32 ? 128 * 32 * 4 : 128 * 32 * 2];
  __shared__ __attribute__((aligned(16))) u16 Bs[128 * 32];
  float* Asf = (float*)AsRaw;
  u16* As16 = (u16*)AsRaw;

  const int t = threadIdx.x;
  const int tileN = blockIdx.x * 128;
  const int tileM = blockIdx.y * 128;
  const int l = t & 63;
  const int w = t >> 6;
  const int wr = (w >> 1) * 64;
  const int wc = (w & 1) * 64;
  const int fr = l & 15;
  const int fg = l >> 4;

  const u16* bsrc[2];
  u16* bdst[2];
#pragma unroll
  for (int j = 0; j < 2; ++j) {
    int tb = w * 1024 + j * 4096 + (t & 63) * 16;
    int row = tb >> 6, gd = (tb >> 4) & 3;
    bsrc[j] = Bp + (size_t)(tileN + row) * K + ((gd ^ ((row >> 1) & 3)) << 3);
    bdst[j] = Bs + w * 512 + j * 2048;
  }
  const float* asrcF[4];
  float* adstF[4];
  const u16* asrcH[2];
  u16* adstH[2];
  if constexpr (AF32) {
#pragma unroll
    for (int j = 0; j < 4; ++j) {
      int tb = w * 1024 + j * 4096 + (t & 63) * 16;
      int row = tb >> 7, gd = (tb >> 4) & 7;
      asrcF[j] = (const float*)Ap + (size_t)(tileM + row) * K + ((gd ^ (row & 7)) << 2);
      adstF[j] = Asf + w * 256 + j * 1024;
    }
  } else {
#pragma unroll
    for (int j = 0; j < 2; ++j) {
      int tb = w * 1024 + j * 4096 + (t & 63) * 16;
      int row = tb >> 6, gd = (tb >> 4) & 3;
      asrcH[j] = (const u16*)Ap + (size_t)(tileM + row) * K + ((gd ^ ((row >> 1) & 3)) << 3);
      adstH[j] = As16 + w * 512 + j * 2048;
    }
  }

  f32x4 acc[4][4];
#pragma unroll
  for (int m = 0; m < 4; ++m)
#pragma unroll
    for (int n = 0; n < 4; ++n) {
      f32x4 z = {0.f, 0.f, 0.f, 0.f};
      acc[m][n] = z;
    }

  for (int k0 = 0; k0 < K; k0 += 32) {
#pragma unroll
    for (int j = 0; j < 2; ++j) { gl16(bsrc[j], bdst[j]); bsrc[j] += 32; }
    if constexpr (AF32) {
#pragma unroll
      for (int j = 0; j < 4; ++j) { gl16(asrcF[j], adstF[j]); asrcF[j] += 32; }
    } else {
#pragma unroll
      for (int j = 0; j < 2; ++j) { gl16(asrcH[j], adstH[j]); asrcH[j] += 32; }
    }
    __syncthreads();

    bf16x8 av[4], bv[4];
#pragma unroll
    for (int m = 0; m < 4; ++m) {
      const int row = wr + m * 16 + fr;
      if constexpr (AF32) {
        const int g0 = (2 * fg) ^ (row & 7);
        const int g1 = (2 * fg + 1) ^ (row & 7);
        float4 p0 = *(const float4*)(Asf + row * 32 + g0 * 4);
        float4 p1 = *(const float4*)(Asf + row * 32 + g1 * 4);
        uint4 u;
        u.x = cvtpk(p0.x, p0.y); u.y = cvtpk(p0.z, p0.w);
        u.z = cvtpk(p1.x, p1.y); u.w = cvtpk(p1.z, p1.w);
        av[m] = __builtin_bit_cast(bf16x8, u);
      } else {
        const int g = fg ^ ((row >> 1) & 3);
        av[m] = __builtin_bit_cast(bf16x8, *(const u16x8*)(As16 + row * 32 + g * 8));
      }
    }
#pragma unroll
    for (int n = 0; n < 4; ++n) {
      const int row = wc + n * 16 + fr;
      const int g = fg ^ ((row >> 1) & 3);
      bv[n] = __builtin_bit_cast(bf16x8, *(const u16x8*)(Bs + row * 32 + g * 8));
    }
#pragma unroll
    for (int m = 0; m < 4; ++m)
#pragma unroll
      for (int n = 0; n < 4; ++n)
        acc[m][n] = mfma16(av[m], bv[n], acc[m][n]);
    __syncthreads();
  }

#pragma unroll
  for (int m = 0; m < 4; ++m) {
#pragma unroll
    for (int n = 0; n < 4; ++n) {
      const int gcol = tileN + wc + n * 16 + fr;
      const int growb = tileM + wr + m * 16 + fg * 4;
#pragma unroll
      for (int r = 0; r < 4; ++r) {
        const int grow = growb + r;
        float v = acc[m][n][r];
        if constexpr (EPI == EPI_GATES) {
          v += bias[gcol];   // b_ih + b_hh folded here
          ((u16*)Cp)[(size_t)grow * ldc + gcol] = f2b(v);
        } else if constexpr (EPI == EPI_H1) {
          v += bias[(grow >> 7) * 256 + gcol];
          v = fmaxf(v, 0.f);
          ((u16*)Cp)[(size_t)grow * ldc + gcol] = f2b(v);
        } else if constexpr (EPI == EPI_H2) {
          v += bias[gcol];
          v = fmaxf(v, 0.f);
          ((u16*)Cp)[(size_t)grow * ldc + gcol] = f2b(v);
        } else {
          v += bias[gcol];
          ((float*)Cp)[(size_t)grow * ldc + gcol] = sigf(v);
        }
      }
    }
  }
}

// ---------------- fused LSTM scan + encoder + VQ + p1 ----------------
// 448 threads (7 waves), one block per batch (R9 structure, proven 268us).
// W_hh now i4 in LDS (k 0..191, 75KB dyn-shared) + 1 tail dword x2 rows in
// regs. Worker r<400 computes gate rows {r, r+400}: per jb 2 uint4 LDS reads
// (was 4 at i8) -> LDS issue ~2100 cyc/step (was ~3100); unpack i4->i8 (5
// VALU / packed dword) + sdot4. h stays i8 (13 broadcast reads).
__global__ __launch_bounds__(448) void lstm_enc(
    const u16* __restrict__ gates, const uint4* __restrict__ W4g,
    const uint2* __restrict__ Wreg2,
    const float* __restrict__ Wenc, const float* __restrict__ b_enc,
    const float* __restrict__ emb, const float* __restrict__ W1,
    const float* __restrict__ b1, const float* __restrict__ noise,
    float* __restrict__ p1) {
  extern __shared__ __attribute__((aligned(16))) char dynsm[];
  uint4* W4 = (uint4*)dynsm;                       // [6*800] uint4 (i4-packed)
  __shared__ __attribute__((aligned(16))) unsigned sh_hq[56];  // h as i8 (pad 0)
  __shared__ __attribute__((aligned(16))) float sh_hf[HID];
  __shared__ float sh_g[G4H];
  __shared__ __attribute__((aligned(16))) float sh_ze[LATENT];
  __shared__ float sh_zq[LATENT];
  __shared__ float sh_rd[448];
  __shared__ int sh_ri[448];
  const int r = threadIdx.x;
  const int b = blockIdx.x;
  const bool active = (r < 400);

  for (int i = r; i < W4_UINT4; i += 448) W4[i] = W4g[i];
  uint2 wreg = active ? Wreg2[r] : (uint2){0, 0};
  if (r < 56) sh_hq[r] = 0;
  if (r < HID) sh_hf[r] = 0.f;
  float c = 0.f;
  const u16* gp = gates + (size_t)b * TLEN * LDG + r;
  float gvA = 0.f, gvB = 0.f;
  if (active) { gvA = b2f(gp[0]); gvB = b2f(gp[400]); }
  __syncthreads();

  for (int t = 0; t < TLEN; ++t) {
    gp += LDG;
    float gvA_n = 0.f, gvB_n = 0.f;
    if (active && t + 1 < TLEN) { gvA_n = b2f(gp[0]); gvB_n = b2f(gp[400]); }

    if (active) {
      unsigned hd[52];
#pragma unroll
      for (int j = 0; j < 13; ++j) {
        uint4 v = ((const uint4*)sh_hq)[j];
        hd[4 * j + 0] = v.x; hd[4 * j + 1] = v.y;
        hd[4 * j + 2] = v.z; hd[4 * j + 3] = v.w;
      }
      int accA = 0, accB = 0;
#pragma unroll
      for (int jb = 0; jb < 6; ++jb) {
        uint4 wA = W4[jb * 800 + r];
        uint4 wB = W4[jb * 800 + 400 + r];
#pragma unroll
        for (int e = 0; e < 4; ++e) {
          unsigned da = (&wA.x)[e], db = (&wB.x)[e];
          unsigned la, ha, lb, hb;
          unp4(da, la, ha);
          unp4(db, lb, hb);
          accA = dot4(la, hd[jb * 8 + 2 * e], accA);
          accA = dot4(ha, hd[jb * 8 + 2 * e + 1], accA);
          accB = dot4(lb, hd[jb * 8 + 2 * e], accB);
          accB = dot4(hb, hd[jb * 8 + 2 * e + 1], accB);
        }
      }
      // tail k 192..199 from registers
      {
        unsigned la, ha;
        unp4(wreg.x, la, ha);
        accA = dot4(la, hd[48], accA);
        accA = dot4(ha, hd[49], accA);
        unp4(wreg.y, la, ha);
        accB = dot4(la, hd[48], accB);
        accB = dot4(ha, hd[49], accB);
      }
      sh_g[r] = gvA + (float)accA * ISCL4;
      sh_g[r + 400] = gvB + (float)accB * ISCL4;
    }
    __syncthreads();  // gates visible; all sh_hq reads complete
    if (r < HID) {
      float gi = sh_g[r], gf = sh_g[HID + r], gg = sh_g[2 * HID + r], go = sh_g[3 * HID + r];
      c = sigf(gf) * c + sigf(gi) * tanh_fast(gg);
      float h = sigf(go) * tanh_fast(c);
      sh_hf[r] = h;
      int q = __float2int_rn(h * HSCL);
      ((char*)sh_hq)[r] = (char)q;
    }
    __syncthreads();  // new h visible
    gvA = gvA_n; gvB = gvB_n;
  }

  // encoder: z_e = h @ Wenc^T + b_enc
  if (r < LATENT) {
    float z = b_enc[r];
#pragma unroll 4
    for (int k = 0; k < HID; ++k) z = fmaf(Wenc[(size_t)r * HID + k], sh_hf[k], z);
    sh_ze[r] = z;
  }
  __syncthreads();

  // VQ: argmin_k ||e_k||^2 - 2 z_e . e_k
  float best = INFINITY; int bi = 0;
  for (int k = r; k < NCODES; k += 448) {
    float d = 0.f;
#pragma unroll
    for (int q = 0; q < LATENT / 4; ++q) {
      float4 e = *(const float4*)&emb[(size_t)k * LATENT + q * 4];
      float4 z = *(const float4*)&sh_ze[q * 4];
      d += e.x * (e.x - 2.f * z.x) + e.y * (e.y - 2.f * z.y)
         + e.z * (e.z - 2.f * z.z) + e.w * (e.w - 2.f * z.w);
    }
    if (d < best) { best = d; bi = k; }
  }
  sh_rd[r] = best; sh_ri[r] = bi;
  __syncthreads();
  for (int s = 256; s > 0; s >>= 1) {
    if (r < s && r + s < 448) {
      float od = sh_rd[r + s]; int oi = sh_ri[r + s];
      if (od < sh_rd[r] || (od == sh_rd[r] && oi < sh_ri[r])) { sh_rd[r] = od; sh_ri[r] = oi; }
    }
    __syncthreads();
  }
  const int kmin = sh_ri[0];
  if (r < LATENT) sh_zq[r] = emb[(size_t)kmin * LATENT + r];
  __syncthreads();

  // p1[b][j] = b1 + W1[:,0:128].zq + W1[:,1664:2432].noise  (pad cols 200..255 = 0)
  if (r < 256) {
    float v = 0.f;
    if (r < HID) {
      v = b1[r];
      const float* wrow = W1 + (size_t)r * 2432;
#pragma unroll 4
      for (int d = 0; d < LATENT; ++d) v = fmaf(wrow[d], sh_zq[d], v);
      const float* nz = noise + (size_t)b * DIN;
#pragma unroll 4
      for (int d = 0; d < DIN; ++d) v = fmaf(wrow[1664 + d], nz[d], v);
    }
    p1[b * 256 + r] = v;
  }
}

// ---------------- host ----------------
extern "C" void kernel_launch(void* const* d_in, const int* in_sizes, int n_in,
                              void* d_out, int out_size, void* d_ws, size_t ws_size,
                              hipStream_t stream) {
  const float* x     = (const float*)d_in[0];
  const float* cond  = (const float*)d_in[1];
  const float* noise = (const float*)d_in[2];
  const float* W_ih  = (const float*)d_in[3];
  const float* W_hh  = (const float*)d_in[4];
  const float* b_ih  = (const float*)d_in[5];
  const float* b_hh  = (const float*)d_in[6];
  const float* W_enc = (const float*)d_in[7];
  const float* b_enc = (const float*)d_in[8];
  const float* emb   = (const float*)d_in[9];
  const float* W1    = (const float*)d_in[10];
  const float* b1    = (const float*)d_in[11];
  const float* W2    = (const float*)d_in[12];
  const float* b2    = (const float*)d_in[13];
  const float* W3    = (const float*)d_in[14];
  const float* b3    = (const float*)d_in[15];

  char* ws = (char*)d_ws;
  size_t off = 0;
  auto alloc = [&](size_t bytes) -> void* {
    void* p = ws + off; off += (bytes + 255) & ~(size_t)255; return p;
  };
  u16*      W_ihb = (u16*)alloc((size_t)896 * 768 * 2);
  u16*      W1cb  = (u16*)alloc((size_t)256 * 1536 * 2);
  u16*      W2b   = (u16*)alloc((size_t)512 * 256 * 2);
  u16*      W3b   = (u16*)alloc((size_t)768 * 512 * 2);
  float*    b2p   = (float*)alloc(512 * 4);
  unsigned* W4    = (unsigned*)alloc((size_t)W4_BYTES);
  unsigned* Wreg  = (unsigned*)alloc((size_t)400 * 2 * 4);
  float*    biasc = (float*)alloc(LDG * 4);
  u16*      gates = (u16*)alloc((size_t)MROWS * LDG * 2);
  float*    p1    = (float*)alloc(256 * 256 * 4);
  u16*      h1    = (u16*)alloc((size_t)MROWS * LDH1 * 2);
  u16*      h2    = (u16*)alloc((size_t)MROWS * LDH2 * 2);

  cvt_pad<<<dim3((896 * 768 + 255) / 256), 256, 0, stream>>>(W_ih, W_ihb, 800, 768, 768, 0, 896, 768);
  cvt_pad<<<dim3((256 * 1536 + 255) / 256), 256, 0, stream>>>(W1, W1cb, 200, 1536, 2432, 128, 256, 1536);
  cvt_pad<<<dim3((512 * 256 + 255) / 256), 256, 0, stream>>>(W2, W2b, 400, 200, 200, 0, 512, 256);
  cvt_pad<<<dim3((768 * 512 + 255) / 256), 256, 0, stream>>>(W3, W3b, 768, 400, 400, 0, 768, 512);
  pad_f32<<<dim3(2), 256, 0, stream>>>(b2, b2p, 400, 512);
  pack_whh_i4<<<dim3((800 * 25 + 255) / 256), 256, 0, stream>>>(W_hh, W4, Wreg, b_ih, b_hh, biasc);

  // gates = x @ W_ih^T + (b_ih + b_hh), bf16 out, ld 896
  gemm_bf16<true, EPI_GATES><<<dim3(LDG / 128, MROWS / 128), 256, 0, stream>>>(
      x, W_ihb, gates, 768, LDG, biasc);

  // LSTM scan + encoder + VQ + p1 (W_hh in dynamic LDS, i4)
  static bool attr_set = false;
  if (!attr_set) {
    (void)hipFuncSetAttribute((const void*)lstm_enc,
                              hipFuncAttributeMaxDynamicSharedMemorySize, W4_BYTES);
    attr_set = true;
  }
  lstm_enc<<<dim3(NB), 448, W4_BYTES, stream>>>(gates, (const uint4*)W4, (const uint2*)Wreg,
                                                W_enc, b_enc, emb, W1, b1, noise, p1);

  // h1 = relu(cond @ W1c^T + p1[b])
  gemm_bf16<true, EPI_H1><<<dim3(LDH1 / 128, MROWS / 128), 256, 0, stream>>>(
      cond, W1cb, h1, DCOND, LDH1, p1);
  // h2 = relu(h1 @ W2^T + b2)
  gemm_bf16<false, EPI_H2><<<dim3(LDH2 / 128, MROWS / 128), 256, 0, stream>>>(
      h1, W2b, h2, LDH1, LDH2, b2p);
  // out = sigmoid(h2 @ W3^T + b3)
  gemm_bf16<false, EPI_OUT><<<dim3(NOUT / 128, MROWS / 128), 256, 0, stream>>>(
      h2, W3b, (float*)d_out, LDH2, NOUT, b3);
}

// Round 14
// 555.413 us; speedup vs baseline: 2.2870x; 1.1245x over previous
//
#include <hip/hip_runtime.h>
#include <math.h>

typedef unsigned short u16;
typedef u16 u16x8 __attribute__((ext_vector_type(8)));
typedef __bf16 bf16x8 __attribute__((ext_vector_type(8)));
typedef float f32x4 __attribute__((ext_vector_type(4)));

#define HID 200
#define G4H 800
#define TLEN 128
#define LATENT 128
#define NCODES 1024
#define DIN 768
#define DCOND 1536
#define NB 256
#define MROWS (NB * TLEN)
#define LDG 896
#define LDH1 256
#define LDH2 512
#define NOUT 768

#define WSCL 400.0f
#define HSCL 127.0f
#define ISCL (1.0f / (WSCL * HSCL))
#define W4_UINT4 (12 * 800)          // k 0..191, i8-packed, [jb][row] uint4
#define W4_BYTES (W4_UINT4 * 16)     // 153600

__device__ __forceinline__ u16 f2b(float f) {
  union { float f; unsigned u; } v; v.f = f;
  unsigned r = v.u + 0x7fffu + ((v.u >> 16) & 1u);
  return (u16)(r >> 16);
}
__device__ __forceinline__ float b2f(u16 h) {
  union { unsigned u; float f; } v; v.u = ((unsigned)h) << 16;
  return v.f;
}
__device__ __forceinline__ float sigf(float x) { return 1.f / (1.f + __expf(-x)); }
__device__ __forceinline__ float tanh_fast(float x) {
  return 1.f - 2.f / (__expf(2.f * x) + 1.f);
}

__device__ __forceinline__ int dot4(unsigned a, unsigned b, int c) {
#if __has_builtin(__builtin_amdgcn_sdot4)
  return __builtin_amdgcn_sdot4((int)a, (int)b, c, false);
#else
  int s = c;
  s += (int)(signed char)(a) * (int)(signed char)(b);
  s += (int)(signed char)(a >> 8) * (int)(signed char)(b >> 8);
  s += (int)(signed char)(a >> 16) * (int)(signed char)(b >> 16);
  s += (int)(signed char)(a >> 24) * (int)(signed char)(b >> 24);
  return s;
#endif
}

// async global->LDS, 16B per lane
__device__ __forceinline__ void gl16(const void* g, void* l) {
  __builtin_amdgcn_global_load_lds(
      (const __attribute__((address_space(1))) void*)g,
      (__attribute__((address_space(3))) void*)l, 16, 0, 0);
}

__device__ __forceinline__ unsigned cvtpk(float a, float b) {
  unsigned r;
  asm("v_cvt_pk_bf16_f32 %0, %1, %2" : "=v"(r) : "v"(a), "v"(b));
  return r;
}

// ---------------- weight convert + pad ----------------
__global__ void cvt_pad(const float* __restrict__ src, u16* __restrict__ dst,
                        int nr, int nc, int lds, int col0, int NRp, int KP) {
  int i = blockIdx.x * blockDim.x + threadIdx.x;
  if (i >= NRp * KP) return;
  int r = i / KP, c = i - r * KP;
  float v = (r < nr && c < nc) ? src[(size_t)r * lds + col0 + c] : 0.f;
  dst[i] = f2b(v);
}

__global__ void pad_f32(const float* __restrict__ src, float* __restrict__ dst,
                        int n, int npad) {
  int i = blockIdx.x * blockDim.x + threadIdx.x;
  if (i < npad) dst[i] = (i < n) ? src[i] : 0.f;
}

// W_hh [800][200] f32 -> i8 (x400 scale):
//   k 0..191  -> W4 dword index (jb*800 + row)*4 + word   (uint4 per [jb][row])
//   k 192..199-> Wreg[u*8 + g*2 + d] for row = g*200+u (worker-r-major tails)
// biasc[col<896] = b_ih+b_hh (0-padded) for the gates-GEMM epilogue.
__global__ void pack_whh_i8(const float* __restrict__ Whh, unsigned* __restrict__ W4,
                            unsigned* __restrict__ Wreg,
                            const float* __restrict__ b_ih, const float* __restrict__ b_hh,
                            float* __restrict__ biasc) {
  int i = blockIdx.x * blockDim.x + threadIdx.x;
  if (i < 800 * 50) {
    int row = i / 50, dw = i - row * 50;
    unsigned d = 0;
#pragma unroll
    for (int e = 0; e < 4; ++e) {
      int k = dw * 4 + e;
      float w = Whh[(size_t)row * HID + k] * WSCL;
      int q = (int)lrintf(w);
      q = q > 127 ? 127 : (q < -127 ? -127 : q);
      d |= ((unsigned)(q & 0xFF)) << (8 * e);
    }
    if (dw < 48) {
      W4[((dw >> 2) * 800 + row) * 4 + (dw & 3)] = d;
    } else {  // dw in {48,49}: k 192..199
      int g = row / 200, u = row - g * 200;
      Wreg[u * 8 + g * 2 + (dw - 48)] = d;
    }
  }
  if (i < LDG) biasc[i] = (i < G4H) ? (b_ih[i] + b_hh[i]) : 0.f;
}

// ---------------- bf16 MFMA GEMM: C[M,N] = A[M,K] * B[N,K]^T (+epilogue) ----------------
enum { EPI_GATES = 0, EPI_H1 = 1, EPI_H2 = 2, EPI_OUT = 3 };

__device__ __forceinline__ f32x4 mfma16(bf16x8 a, bf16x8 b, f32x4 c) {
  return __builtin_amdgcn_mfma_f32_16x16x32_bf16(a, b, c, 0, 0, 0);
}

template<bool AF32, int EPI>
__global__ __launch_bounds__(256) void gemm_bf16(
    const void* __restrict__ Ap, const u16* __restrict__ Bp,
    void* __restrict__ Cp, int K, int ldc, const float* __restrict__ bias) {
  __shared__ __attribute__((aligned(16))) char AsRaw[AF32 ? 128 * 32 * 4 : 128 * 32 * 2];
  __shared__ __attribute__((aligned(16))) u16 Bs[128 * 32];
  float* Asf = (float*)AsRaw;
  u16* As16 = (u16*)AsRaw;

  const int t = threadIdx.x;
  const int tileN = blockIdx.x * 128;
  const int tileM = blockIdx.y * 128;
  const int l = t & 63;
  const int w = t >> 6;
  const int wr = (w >> 1) * 64;
  const int wc = (w & 1) * 64;
  const int fr = l & 15;
  const int fg = l >> 4;

  const u16* bsrc[2];
  u16* bdst[2];
#pragma unroll
  for (int j = 0; j < 2; ++j) {
    int tb = w * 1024 + j * 4096 + (t & 63) * 16;
    int row = tb >> 6, gd = (tb >> 4) & 3;
    bsrc[j] = Bp + (size_t)(tileN + row) * K + ((gd ^ ((row >> 1) & 3)) << 3);
    bdst[j] = Bs + w * 512 + j * 2048;
  }
  const float* asrcF[4];
  float* adstF[4];
  const u16* asrcH[2];
  u16* adstH[2];
  if constexpr (AF32) {
#pragma unroll
    for (int j = 0; j < 4; ++j) {
      int tb = w * 1024 + j * 4096 + (t & 63) * 16;
      int row = tb >> 7, gd = (tb >> 4) & 7;
      asrcF[j] = (const float*)Ap + (size_t)(tileM + row) * K + ((gd ^ (row & 7)) << 2);
      adstF[j] = Asf + w * 256 + j * 1024;
    }
  } else {
#pragma unroll
    for (int j = 0; j < 2; ++j) {
      int tb = w * 1024 + j * 4096 + (t & 63) * 16;
      int row = tb >> 6, gd = (tb >> 4) & 3;
      asrcH[j] = (const u16*)Ap + (size_t)(tileM + row) * K + ((gd ^ ((row >> 1) & 3)) << 3);
      adstH[j] = As16 + w * 512 + j * 2048;
    }
  }

  f32x4 acc[4][4];
#pragma unroll
  for (int m = 0; m < 4; ++m)
#pragma unroll
    for (int n = 0; n < 4; ++n) {
      f32x4 z = {0.f, 0.f, 0.f, 0.f};
      acc[m][n] = z;
    }

  for (int k0 = 0; k0 < K; k0 += 32) {
#pragma unroll
    for (int j = 0; j < 2; ++j) { gl16(bsrc[j], bdst[j]); bsrc[j] += 32; }
    if constexpr (AF32) {
#pragma unroll
      for (int j = 0; j < 4; ++j) { gl16(asrcF[j], adstF[j]); asrcF[j] += 32; }
    } else {
#pragma unroll
      for (int j = 0; j < 2; ++j) { gl16(asrcH[j], adstH[j]); asrcH[j] += 32; }
    }
    __syncthreads();

    bf16x8 av[4], bv[4];
#pragma unroll
    for (int m = 0; m < 4; ++m) {
      const int row = wr + m * 16 + fr;
      if constexpr (AF32) {
        const int g0 = (2 * fg) ^ (row & 7);
        const int g1 = (2 * fg + 1) ^ (row & 7);
        float4 p0 = *(const float4*)(Asf + row * 32 + g0 * 4);
        float4 p1 = *(const float4*)(Asf + row * 32 + g1 * 4);
        uint4 u;
        u.x = cvtpk(p0.x, p0.y); u.y = cvtpk(p0.z, p0.w);
        u.z = cvtpk(p1.x, p1.y); u.w = cvtpk(p1.z, p1.w);
        av[m] = __builtin_bit_cast(bf16x8, u);
      } else {
        const int g = fg ^ ((row >> 1) & 3);
        av[m] = __builtin_bit_cast(bf16x8, *(const u16x8*)(As16 + row * 32 + g * 8));
      }
    }
#pragma unroll
    for (int n = 0; n < 4; ++n) {
      const int row = wc + n * 16 + fr;
      const int g = fg ^ ((row >> 1) & 3);
      bv[n] = __builtin_bit_cast(bf16x8, *(const u16x8*)(Bs + row * 32 + g * 8));
    }
#pragma unroll
    for (int m = 0; m < 4; ++m)
#pragma unroll
      for (int n = 0; n < 4; ++n)
        acc[m][n] = mfma16(av[m], bv[n], acc[m][n]);
    __syncthreads();
  }

#pragma unroll
  for (int m = 0; m < 4; ++m) {
#pragma unroll
    for (int n = 0; n < 4; ++n) {
      const int gcol = tileN + wc + n * 16 + fr;
      const int growb = tileM + wr + m * 16 + fg * 4;
#pragma unroll
      for (int r = 0; r < 4; ++r) {
        const int grow = growb + r;
        float v = acc[m][n][r];
        if constexpr (EPI == EPI_GATES) {
          v += bias[gcol];   // b_ih + b_hh folded here
          ((u16*)Cp)[(size_t)grow * ldc + gcol] = f2b(v);
        } else if constexpr (EPI == EPI_H1) {
          v += bias[(grow >> 7) * 256 + gcol];
          v = fmaxf(v, 0.f);
          ((u16*)Cp)[(size_t)grow * ldc + gcol] = f2b(v);
        } else if constexpr (EPI == EPI_H2) {
          v += bias[gcol];
          v = fmaxf(v, 0.f);
          ((u16*)Cp)[(size_t)grow * ldc + gcol] = f2b(v);
        } else {
          v += bias[gcol];
          ((float*)Cp)[(size_t)grow * ldc + gcol] = sigf(v);
        }
      }
    }
  }
}

// ---------------- fused LSTM scan + encoder + VQ + p1 ----------------
// 256 threads (4 waves), one block per batch. W_hh i8 in LDS (k 0..191,
// 150KB dyn-shared, [jb][row] layout -> lane-contiguous conflict-free reads)
// + 2 tail dwords x4 rows in regs. Worker r<200 owns ALL FOUR gate rows of
// unit r (rows r, 200+r, 400+r, 600+r): activation is worker-local (no sh_g,
// no second barrier); h double-buffered as i8 -> ONE barrier per step.
__global__ __launch_bounds__(256) void lstm_enc(
    const u16* __restrict__ gates, const uint4* __restrict__ W4g,
    const uint4* __restrict__ WregG,
    const float* __restrict__ Wenc, const float* __restrict__ b_enc,
    const float* __restrict__ emb, const float* __restrict__ W1,
    const float* __restrict__ b1, const float* __restrict__ noise,
    float* __restrict__ p1) {
  extern __shared__ __attribute__((aligned(16))) char dynsm[];
  uint4* W4 = (uint4*)dynsm;                       // [12*800] uint4 (i8)
  __shared__ __attribute__((aligned(16))) unsigned sh_hq[2][56];  // h i8, dbuf, pad 0
  __shared__ __attribute__((aligned(16))) float sh_hf[HID];
  __shared__ __attribute__((aligned(16))) float sh_ze[LATENT];
  __shared__ float sh_zq[LATENT];
  __shared__ float sh_rd[256];
  __shared__ int sh_ri[256];
  const int r = threadIdx.x;
  const int b = blockIdx.x;
  const bool worker = (r < 200);

  // stage W4 into LDS (9600 uint4, coalesced; L2-resident source)
  for (int i = r; i < W4_UINT4; i += 256) W4[i] = W4g[i];
  uint4 wt0 = {0, 0, 0, 0}, wt1 = {0, 0, 0, 0};
  if (worker) { wt0 = WregG[r * 2]; wt1 = WregG[r * 2 + 1]; }
  if (r < 56) { sh_hq[0][r] = 0; sh_hq[1][r] = 0; }
  float c = 0.f, hlast = 0.f;
  const u16* gp = gates + (size_t)b * TLEN * LDG + r;
  float gv0 = 0.f, gv1 = 0.f, gv2 = 0.f, gv3 = 0.f;
  if (worker) {
    gv0 = b2f(gp[0]); gv1 = b2f(gp[200]);
    gv2 = b2f(gp[400]); gv3 = b2f(gp[600]);
  }
  __syncthreads();

  for (int t = 0; t < TLEN; ++t) {
    gp += LDG;
    float gn0 = 0.f, gn1 = 0.f, gn2 = 0.f, gn3 = 0.f;
    if (worker && t + 1 < TLEN) {
      gn0 = b2f(gp[0]); gn1 = b2f(gp[200]);
      gn2 = b2f(gp[400]); gn3 = b2f(gp[600]);
    }
    const int cur = t & 1, nxt = cur ^ 1;

    if (worker) {
      unsigned hd[52];
#pragma unroll
      for (int j = 0; j < 13; ++j) {
        uint4 v = ((const uint4*)sh_hq[cur])[j];
        hd[4 * j + 0] = v.x; hd[4 * j + 1] = v.y;
        hd[4 * j + 2] = v.z; hd[4 * j + 3] = v.w;
      }
      int a0 = 0, a1 = 0, a2 = 0, a3 = 0;
#pragma unroll
      for (int jb = 0; jb < 12; ++jb) {
        uint4 w0 = W4[jb * 800 + r];
        uint4 w1 = W4[jb * 800 + 200 + r];
        uint4 w2 = W4[jb * 800 + 400 + r];
        uint4 w3 = W4[jb * 800 + 600 + r];
#pragma unroll
        for (int e = 0; e < 4; ++e) {
          unsigned h = hd[jb * 4 + e];
          a0 = dot4((&w0.x)[e], h, a0);
          a1 = dot4((&w1.x)[e], h, a1);
          a2 = dot4((&w2.x)[e], h, a2);
          a3 = dot4((&w3.x)[e], h, a3);
        }
      }
      // tail k 192..199 from registers
      a0 = dot4(wt0.x, hd[48], a0); a0 = dot4(wt0.y, hd[49], a0);
      a1 = dot4(wt0.z, hd[48], a1); a1 = dot4(wt0.w, hd[49], a1);
      a2 = dot4(wt1.x, hd[48], a2); a2 = dot4(wt1.y, hd[49], a2);
      a3 = dot4(wt1.z, hd[48], a3); a3 = dot4(wt1.w, hd[49], a3);
      float gi = gv0 + (float)a0 * ISCL;
      float gf = gv1 + (float)a1 * ISCL;
      float gg = gv2 + (float)a2 * ISCL;
      float go = gv3 + (float)a3 * ISCL;
      c = sigf(gf) * c + sigf(gi) * tanh_fast(gg);
      hlast = sigf(go) * tanh_fast(c);
      ((char*)sh_hq[nxt])[r] = (char)__float2int_rn(hlast * HSCL);
    }
    __syncthreads();  // h(t+1) visible; prior reads of buf[nxt] finished last step
    gv0 = gn0; gv1 = gn1; gv2 = gn2; gv3 = gn3;
  }

  if (worker) sh_hf[r] = hlast;
  __syncthreads();

  // encoder: z_e = h @ Wenc^T + b_enc
  if (r < LATENT) {
    float z = b_enc[r];
#pragma unroll 4
    for (int k = 0; k < HID; ++k) z = fmaf(Wenc[(size_t)r * HID + k], sh_hf[k], z);
    sh_ze[r] = z;
  }
  __syncthreads();

  // VQ: argmin_k ||e_k||^2 - 2 z_e . e_k
  float best = INFINITY; int bi = 0;
  for (int k = r; k < NCODES; k += 256) {
    float d = 0.f;
#pragma unroll
    for (int q = 0; q < LATENT / 4; ++q) {
      float4 e = *(const float4*)&emb[(size_t)k * LATENT + q * 4];
      float4 z = *(const float4*)&sh_ze[q * 4];
      d += e.x * (e.x - 2.f * z.x) + e.y * (e.y - 2.f * z.y)
         + e.z * (e.z - 2.f * z.z) + e.w * (e.w - 2.f * z.w);
    }
    if (d < best) { best = d; bi = k; }
  }
  sh_rd[r] = best; sh_ri[r] = bi;
  __syncthreads();
  for (int s = 128; s > 0; s >>= 1) {
    if (r < s) {
      float od = sh_rd[r + s]; int oi = sh_ri[r + s];
      if (od < sh_rd[r] || (od == sh_rd[r] && oi < sh_ri[r])) { sh_rd[r] = od; sh_ri[r] = oi; }
    }
    __syncthreads();
  }
  const int kmin = sh_ri[0];
  if (r < LATENT) sh_zq[r] = emb[(size_t)kmin * LATENT + r];
  __syncthreads();

  // p1[b][j] = b1 + W1[:,0:128].zq + W1[:,1664:2432].noise  (pad cols 200..255 = 0)
  {
    float v = 0.f;
    if (worker) {
      v = b1[r];
      const float* wrow = W1 + (size_t)r * 2432;
#pragma unroll 4
      for (int d = 0; d < LATENT; ++d) v = fmaf(wrow[d], sh_zq[d], v);
      const float* nz = noise + (size_t)b * DIN;
#pragma unroll 4
      for (int d = 0; d < DIN; ++d) v = fmaf(wrow[1664 + d], nz[d], v);
    }
    p1[b * 256 + r] = v;
  }
}

// ---------------- host ----------------
extern "C" void kernel_launch(void* const* d_in, const int* in_sizes, int n_in,
                              void* d_out, int out_size, void* d_ws, size_t ws_size,
                              hipStream_t stream) {
  const float* x     = (const float*)d_in[0];
  const float* cond  = (const float*)d_in[1];
  const float* noise = (const float*)d_in[2];
  const float* W_ih  = (const float*)d_in[3];
  const float* W_hh  = (const float*)d_in[4];
  const float* b_ih  = (const float*)d_in[5];
  const float* b_hh  = (const float*)d_in[6];
  const float* W_enc = (const float*)d_in[7];
  const float* b_enc = (const float*)d_in[8];
  const float* emb   = (const float*)d_in[9];
  const float* W1    = (const float*)d_in[10];
  const float* b1    = (const float*)d_in[11];
  const float* W2    = (const float*)d_in[12];
  const float* b2    = (const float*)d_in[13];
  const float* W3    = (const float*)d_in[14];
  const float* b3    = (const float*)d_in[15];

  char* ws = (char*)d_ws;
  size_t off = 0;
  auto alloc = [&](size_t bytes) -> void* {
    void* p = ws + off; off += (bytes + 255) & ~(size_t)255; return p;
  };
  u16*      W_ihb = (u16*)alloc((size_t)896 * 768 * 2);
  u16*      W1cb  = (u16*)alloc((size_t)256 * 1536 * 2);
  u16*      W2b   = (u16*)alloc((size_t)512 * 256 * 2);
  u16*      W3b   = (u16*)alloc((size_t)768 * 512 * 2);
  float*    b2p   = (float*)alloc(512 * 4);
  unsigned* W4    = (unsigned*)alloc((size_t)W4_BYTES);
  unsigned* Wreg  = (unsigned*)alloc((size_t)200 * 8 * 4);
  float*    biasc = (float*)alloc(LDG * 4);
  u16*      gates = (u16*)alloc((size_t)MROWS * LDG * 2);
  float*    p1    = (float*)alloc(256 * 256 * 4);
  u16*      h1    = (u16*)alloc((size_t)MROWS * LDH1 * 2);
  u16*      h2    = (u16*)alloc((size_t)MROWS * LDH2 * 2);

  cvt_pad<<<dim3((896 * 768 + 255) / 256), 256, 0, stream>>>(W_ih, W_ihb, 800, 768, 768, 0, 896, 768);
  cvt_pad<<<dim3((256 * 1536 + 255) / 256), 256, 0, stream>>>(W1, W1cb, 200, 1536, 2432, 128, 256, 1536);
  cvt_pad<<<dim3((512 * 256 + 255) / 256), 256, 0, stream>>>(W2, W2b, 400, 200, 200, 0, 512, 256);
  cvt_pad<<<dim3((768 * 512 + 255) / 256), 256, 0, stream>>>(W3, W3b, 768, 400, 400, 0, 768, 512);
  pad_f32<<<dim3(2), 256, 0, stream>>>(b2, b2p, 400, 512);
  pack_whh_i8<<<dim3((800 * 50 + 255) / 256), 256, 0, stream>>>(W_hh, W4, Wreg, b_ih, b_hh, biasc);

  // gates = x @ W_ih^T + (b_ih + b_hh), bf16 out, ld 896
  gemm_bf16<true, EPI_GATES><<<dim3(LDG / 128, MROWS / 128), 256, 0, stream>>>(
      x, W_ihb, gates, 768, LDG, biasc);

  // LSTM scan + encoder + VQ + p1 (W_hh in dynamic LDS, i8; 256 thr)
  static bool attr_set = false;
  if (!attr_set) {
    (void)hipFuncSetAttribute((const void*)lstm_enc,
                              hipFuncAttributeMaxDynamicSharedMemorySize, W4_BYTES);
    attr_set = true;
  }
  lstm_enc<<<dim3(NB), 256, W4_BYTES, stream>>>(gates, (const uint4*)W4, (const uint4*)Wreg,
                                                W_enc, b_enc, emb, W1, b1, noise, p1);

  // h1 = relu(cond @ W1c^T + p1[b])
  gemm_bf16<true, EPI_H1><<<dim3(LDH1 / 128, MROWS / 128), 256, 0, stream>>>(
      cond, W1cb, h1, DCOND, LDH1, p1);
  // h2 = relu(h1 @ W2^T + b2)
  gemm_bf16<false, EPI_H2><<<dim3(LDH2 / 128, MROWS / 128), 256, 0, stream>>>(
      h1, W2b, h2, LDH1, LDH2, b2p);
  // out = sigmoid(h2 @ W3^T + b3)
  gemm_bf16<false, EPI_OUT><<<dim3(NOUT / 128, MROWS / 128), 256, 0, stream>>>(
      h2, W3b, (float*)d_out, LDH2, NOUT, b3);
}

// Round 15
// 524.356 us; speedup vs baseline: 2.4224x; 1.0592x over previous
//
#include <hip/hip_runtime.h>
#include <math.h>

typedef unsigned short u16;
typedef u16 u16x8 __attribute__((ext_vector_type(8)));
typedef __bf16 bf16x8 __attribute__((ext_vector_type(8)));
typedef float f32x4 __attribute__((ext_vector_type(4)));

#define HID 200
#define G4H 800
#define TLEN 128
#define LATENT 128
#define NCODES 1024
#define DIN 768
#define DCOND 1536
#define NB 256
#define MROWS (NB * TLEN)
#define LDG 896
#define LDH1 256
#define LDH2 512
#define NOUT 768

#define WSCL 400.0f
#define HSCL 127.0f
#define ISCL (1.0f / (WSCL * HSCL))
#define W4_UINT4 (12 * 800)          // k 0..191, i8-packed, [jb][row] uint4
#define W4_BYTES (W4_UINT4 * 16)     // 153600

__device__ __forceinline__ u16 f2b(float f) {
  union { float f; unsigned u; } v; v.f = f;
  unsigned r = v.u + 0x7fffu + ((v.u >> 16) & 1u);
  return (u16)(r >> 16);
}
__device__ __forceinline__ float b2f(u16 h) {
  union { unsigned u; float f; } v; v.u = ((unsigned)h) << 16;
  return v.f;
}
__device__ __forceinline__ float sigf(float x) { return 1.f / (1.f + __expf(-x)); }
__device__ __forceinline__ float tanh_fast(float x) {
  return 1.f - 2.f / (__expf(2.f * x) + 1.f);
}

__device__ __forceinline__ int dot4(unsigned a, unsigned b, int c) {
#if __has_builtin(__builtin_amdgcn_sdot4)
  return __builtin_amdgcn_sdot4((int)a, (int)b, c, false);
#else
  int s = c;
  s += (int)(signed char)(a) * (int)(signed char)(b);
  s += (int)(signed char)(a >> 8) * (int)(signed char)(b >> 8);
  s += (int)(signed char)(a >> 16) * (int)(signed char)(b >> 16);
  s += (int)(signed char)(a >> 24) * (int)(signed char)(b >> 24);
  return s;
#endif
}

// async global->LDS, 16B per lane
__device__ __forceinline__ void gl16(const void* g, void* l) {
  __builtin_amdgcn_global_load_lds(
      (const __attribute__((address_space(1))) void*)g,
      (__attribute__((address_space(3))) void*)l, 16, 0, 0);
}

__device__ __forceinline__ unsigned cvtpk(float a, float b) {
  unsigned r;
  asm("v_cvt_pk_bf16_f32 %0, %1, %2" : "=v"(r) : "v"(a), "v"(b));
  return r;
}

// ---------------- weight convert + pad ----------------
__global__ void cvt_pad(const float* __restrict__ src, u16* __restrict__ dst,
                        int nr, int nc, int lds, int col0, int NRp, int KP) {
  int i = blockIdx.x * blockDim.x + threadIdx.x;
  if (i >= NRp * KP) return;
  int r = i / KP, c = i - r * KP;
  float v = (r < nr && c < nc) ? src[(size_t)r * lds + col0 + c] : 0.f;
  dst[i] = f2b(v);
}

__global__ void pad_f32(const float* __restrict__ src, float* __restrict__ dst,
                        int n, int npad) {
  int i = blockIdx.x * blockDim.x + threadIdx.x;
  if (i < npad) dst[i] = (i < n) ? src[i] : 0.f;
}

// W_hh [800][200] f32 -> i8 (x400 scale):
//   k 0..191  -> W4 dword index (jb*800 + row)*4 + word   (uint4 per [jb][row])
//   k 192..199-> Wreg[u*8 + g*2 + d] for row = g*200+u (worker-u-major tails)
// biasc[col<896] = b_ih+b_hh (0-padded) for the gates-GEMM epilogue.
__global__ void pack_whh_i8(const float* __restrict__ Whh, unsigned* __restrict__ W4,
                            unsigned* __restrict__ Wreg,
                            const float* __restrict__ b_ih, const float* __restrict__ b_hh,
                            float* __restrict__ biasc) {
  int i = blockIdx.x * blockDim.x + threadIdx.x;
  if (i < 800 * 50) {
    int row = i / 50, dw = i - row * 50;
    unsigned d = 0;
#pragma unroll
    for (int e = 0; e < 4; ++e) {
      int k = dw * 4 + e;
      float w = Whh[(size_t)row * HID + k] * WSCL;
      int q = (int)lrintf(w);
      q = q > 127 ? 127 : (q < -127 ? -127 : q);
      d |= ((unsigned)(q & 0xFF)) << (8 * e);
    }
    if (dw < 48) {
      W4[((dw >> 2) * 800 + row) * 4 + (dw & 3)] = d;
    } else {  // dw in {48,49}: k 192..199
      int g = row / 200, u = row - g * 200;
      Wreg[u * 8 + g * 2 + (dw - 48)] = d;
    }
  }
  if (i < LDG) biasc[i] = (i < G4H) ? (b_ih[i] + b_hh[i]) : 0.f;
}

// ---------------- bf16 MFMA GEMM: C[M,N] = A[M,K] * B[N,K]^T (+epilogue) ----------------
enum { EPI_GATES = 0, EPI_H1 = 1, EPI_H2 = 2, EPI_OUT = 3 };

__device__ __forceinline__ f32x4 mfma16(bf16x8 a, bf16x8 b, f32x4 c) {
  return __builtin_amdgcn_mfma_f32_16x16x32_bf16(a, b, c, 0, 0, 0);
}

template<bool AF32, int EPI>
__global__ __launch_bounds__(256) void gemm_bf16(
    const void* __restrict__ Ap, const u16* __restrict__ Bp,
    void* __restrict__ Cp, int K, int ldc, const float* __restrict__ bias) {
  __shared__ __attribute__((aligned(16))) char AsRaw[AF32 ? 128 * 32 * 4 : 128 * 32 * 2];
  __shared__ __attribute__((aligned(16))) u16 Bs[128 * 32];
  float* Asf = (float*)AsRaw;
  u16* As16 = (u16*)AsRaw;

  const int t = threadIdx.x;
  const int tileN = blockIdx.x * 128;
  const int tileM = blockIdx.y * 128;
  const int l = t & 63;
  const int w = t >> 6;
  const int wr = (w >> 1) * 64;
  const int wc = (w & 1) * 64;
  const int fr = l & 15;
  const int fg = l >> 4;

  const u16* bsrc[2];
  u16* bdst[2];
#pragma unroll
  for (int j = 0; j < 2; ++j) {
    int tb = w * 1024 + j * 4096 + (t & 63) * 16;
    int row = tb >> 6, gd = (tb >> 4) & 3;
    bsrc[j] = Bp + (size_t)(tileN + row) * K + ((gd ^ ((row >> 1) & 3)) << 3);
    bdst[j] = Bs + w * 512 + j * 2048;
  }
  const float* asrcF[4];
  float* adstF[4];
  const u16* asrcH[2];
  u16* adstH[2];
  if constexpr (AF32) {
#pragma unroll
    for (int j = 0; j < 4; ++j) {
      int tb = w * 1024 + j * 4096 + (t & 63) * 16;
      int row = tb >> 7, gd = (tb >> 4) & 7;
      asrcF[j] = (const float*)Ap + (size_t)(tileM + row) * K + ((gd ^ (row & 7)) << 2);
      adstF[j] = Asf + w * 256 + j * 1024;
    }
  } else {
#pragma unroll
    for (int j = 0; j < 2; ++j) {
      int tb = w * 1024 + j * 4096 + (t & 63) * 16;
      int row = tb >> 6, gd = (tb >> 4) & 3;
      asrcH[j] = (const u16*)Ap + (size_t)(tileM + row) * K + ((gd ^ ((row >> 1) & 3)) << 3);
      adstH[j] = As16 + w * 512 + j * 2048;
    }
  }

  f32x4 acc[4][4];
#pragma unroll
  for (int m = 0; m < 4; ++m)
#pragma unroll
    for (int n = 0; n < 4; ++n) {
      f32x4 z = {0.f, 0.f, 0.f, 0.f};
      acc[m][n] = z;
    }

  for (int k0 = 0; k0 < K; k0 += 32) {
#pragma unroll
    for (int j = 0; j < 2; ++j) { gl16(bsrc[j], bdst[j]); bsrc[j] += 32; }
    if constexpr (AF32) {
#pragma unroll
      for (int j = 0; j < 4; ++j) { gl16(asrcF[j], adstF[j]); asrcF[j] += 32; }
    } else {
#pragma unroll
      for (int j = 0; j < 2; ++j) { gl16(asrcH[j], adstH[j]); asrcH[j] += 32; }
    }
    __syncthreads();

    bf16x8 av[4], bv[4];
#pragma unroll
    for (int m = 0; m < 4; ++m) {
      const int row = wr + m * 16 + fr;
      if constexpr (AF32) {
        const int g0 = (2 * fg) ^ (row & 7);
        const int g1 = (2 * fg + 1) ^ (row & 7);
        float4 p0 = *(const float4*)(Asf + row * 32 + g0 * 4);
        float4 p1 = *(const float4*)(Asf + row * 32 + g1 * 4);
        uint4 u;
        u.x = cvtpk(p0.x, p0.y); u.y = cvtpk(p0.z, p0.w);
        u.z = cvtpk(p1.x, p1.y); u.w = cvtpk(p1.z, p1.w);
        av[m] = __builtin_bit_cast(bf16x8, u);
      } else {
        const int g = fg ^ ((row >> 1) & 3);
        av[m] = __builtin_bit_cast(bf16x8, *(const u16x8*)(As16 + row * 32 + g * 8));
      }
    }
#pragma unroll
    for (int n = 0; n < 4; ++n) {
      const int row = wc + n * 16 + fr;
      const int g = fg ^ ((row >> 1) & 3);
      bv[n] = __builtin_bit_cast(bf16x8, *(const u16x8*)(Bs + row * 32 + g * 8));
    }
#pragma unroll
    for (int m = 0; m < 4; ++m)
#pragma unroll
      for (int n = 0; n < 4; ++n)
        acc[m][n] = mfma16(av[m], bv[n], acc[m][n]);
    __syncthreads();
  }

#pragma unroll
  for (int m = 0; m < 4; ++m) {
#pragma unroll
    for (int n = 0; n < 4; ++n) {
      const int gcol = tileN + wc + n * 16 + fr;
      const int growb = tileM + wr + m * 16 + fg * 4;
#pragma unroll
      for (int r = 0; r < 4; ++r) {
        const int grow = growb + r;
        float v = acc[m][n][r];
        if constexpr (EPI == EPI_GATES) {
          v += bias[gcol];   // b_ih + b_hh folded here
          ((u16*)Cp)[(size_t)grow * ldc + gcol] = f2b(v);
        } else if constexpr (EPI == EPI_H1) {
          v += bias[(grow >> 7) * 256 + gcol];
          v = fmaxf(v, 0.f);
          ((u16*)Cp)[(size_t)grow * ldc + gcol] = f2b(v);
        } else if constexpr (EPI == EPI_H2) {
          v += bias[gcol];
          v = fmaxf(v, 0.f);
          ((u16*)Cp)[(size_t)grow * ldc + gcol] = f2b(v);
        } else {
          v += bias[gcol];
          ((float*)Cp)[(size_t)grow * ldc + gcol] = sigf(v);
        }
      }
    }
  }
}

// ---------------- fused LSTM scan + encoder + VQ + p1 ----------------
// 512 threads (8 waves = 2/SIMD), one block per batch. W_hh i8 in LDS
// ([jb][row] uint4, conflict-free) + tail dwords in regs. K-SPLIT: worker
// r<400 = (u = r%200, kh = r/200); kh=0 does k 0..95 + tail, kh=1 does
// k 96..191, each for ALL FOUR gate rows of unit u. kh=1 writes 4 int
// partials; kh=0 adds + activation (worker-local) + h-write. 2 barriers/step.
// Same integer math as R14 -> bit-identical result; 2x waves/SIMD hides
// the ds_read latency that capped R14 at 5060 cyc/step.
__global__ __launch_bounds__(512) void lstm_enc(
    const u16* __restrict__ gates, const uint4* __restrict__ W4g,
    const uint4* __restrict__ WregG,
    const float* __restrict__ Wenc, const float* __restrict__ b_enc,
    const float* __restrict__ emb, const float* __restrict__ W1,
    const float* __restrict__ b1, const float* __restrict__ noise,
    float* __restrict__ p1) {
  extern __shared__ __attribute__((aligned(16))) char dynsm[];
  uint4* W4 = (uint4*)dynsm;                       // [12*800] uint4 (i8)
  __shared__ __attribute__((aligned(16))) unsigned sh_hq[2][56];  // h i8, dbuf, pad 0
  __shared__ __attribute__((aligned(16))) int sh_p[4][208];       // kh=1 partials
  __shared__ __attribute__((aligned(16))) float sh_hf[HID];
  __shared__ __attribute__((aligned(16))) float sh_ze[LATENT];
  __shared__ float sh_zq[LATENT];
  __shared__ float sh_rd[512];
  __shared__ int sh_ri[512];
  const int r = threadIdx.x;
  const int b = blockIdx.x;
  const bool act = (r < 400);
  const int u = (r < 200) ? r : r - 200;
  const bool lo = (r < 200);        // kh = 0
  const bool hi = act && !lo;       // kh = 1

  // stage W4 into LDS (9600 uint4, coalesced; L2-resident source)
  for (int i = r; i < W4_UINT4; i += 512) W4[i] = W4g[i];
  uint4 wt0 = {0, 0, 0, 0}, wt1 = {0, 0, 0, 0};
  if (lo) { wt0 = WregG[u * 2]; wt1 = WregG[u * 2 + 1]; }
  if (r < 56) { sh_hq[0][r] = 0; sh_hq[1][r] = 0; }
  float c = 0.f, hlast = 0.f;
  const u16* gp = gates + (size_t)b * TLEN * LDG + u;
  float gv0 = 0.f, gv1 = 0.f, gv2 = 0.f, gv3 = 0.f;
  if (lo) {
    gv0 = b2f(gp[0]); gv1 = b2f(gp[200]);
    gv2 = b2f(gp[400]); gv3 = b2f(gp[600]);
  }
  __syncthreads();

  for (int t = 0; t < TLEN; ++t) {
    gp += LDG;
    float gn0 = 0.f, gn1 = 0.f, gn2 = 0.f, gn3 = 0.f;
    if (lo && t + 1 < TLEN) {
      gn0 = b2f(gp[0]); gn1 = b2f(gp[200]);
      gn2 = b2f(gp[400]); gn3 = b2f(gp[600]);
    }
    const int cur = t & 1, nxt = cur ^ 1;

    int a0 = 0, a1 = 0, a2 = 0, a3 = 0;
    if (act) {
      const int jb0 = lo ? 0 : 6;
      unsigned hd[24];
#pragma unroll
      for (int j = 0; j < 6; ++j) {
        uint4 v = ((const uint4*)sh_hq[cur])[(lo ? 0 : 6) + j];
        hd[4 * j + 0] = v.x; hd[4 * j + 1] = v.y;
        hd[4 * j + 2] = v.z; hd[4 * j + 3] = v.w;
      }
#pragma unroll
      for (int j = 0; j < 6; ++j) {
        const int jb = jb0 + j;
        uint4 w0 = W4[jb * 800 + u];
        uint4 w1 = W4[jb * 800 + 200 + u];
        uint4 w2 = W4[jb * 800 + 400 + u];
        uint4 w3 = W4[jb * 800 + 600 + u];
#pragma unroll
        for (int e = 0; e < 4; ++e) {
          unsigned h = hd[j * 4 + e];
          a0 = dot4((&w0.x)[e], h, a0);
          a1 = dot4((&w1.x)[e], h, a1);
          a2 = dot4((&w2.x)[e], h, a2);
          a3 = dot4((&w3.x)[e], h, a3);
        }
      }
      if (hi) {
        sh_p[0][u] = a0; sh_p[1][u] = a1;
        sh_p[2][u] = a2; sh_p[3][u] = a3;
      }
    }
    if (lo) {
      // tail k 192..199 from registers
      uint2 ht = *(const uint2*)&sh_hq[cur][48];
      a0 = dot4(wt0.x, ht.x, a0); a0 = dot4(wt0.y, ht.y, a0);
      a1 = dot4(wt0.z, ht.x, a1); a1 = dot4(wt0.w, ht.y, a1);
      a2 = dot4(wt1.x, ht.x, a2); a2 = dot4(wt1.y, ht.y, a2);
      a3 = dot4(wt1.z, ht.x, a3); a3 = dot4(wt1.w, ht.y, a3);
    }
    __syncthreads();   // kh=1 partials visible
    if (lo) {
      float gi = gv0 + (float)(a0 + sh_p[0][u]) * ISCL;
      float gf = gv1 + (float)(a1 + sh_p[1][u]) * ISCL;
      float gg = gv2 + (float)(a2 + sh_p[2][u]) * ISCL;
      float go = gv3 + (float)(a3 + sh_p[3][u]) * ISCL;
      c = sigf(gf) * c + sigf(gi) * tanh_fast(gg);
      hlast = sigf(go) * tanh_fast(c);
      ((char*)sh_hq[nxt])[u] = (char)__float2int_rn(hlast * HSCL);
    }
    __syncthreads();   // h(t+1) visible; sh_p free for reuse
    gv0 = gn0; gv1 = gn1; gv2 = gn2; gv3 = gn3;
  }

  if (lo) sh_hf[u] = hlast;
  __syncthreads();

  // encoder: z_e = h @ Wenc^T + b_enc
  if (r < LATENT) {
    float z = b_enc[r];
#pragma unroll 4
    for (int k = 0; k < HID; ++k) z = fmaf(Wenc[(size_t)r * HID + k], sh_hf[k], z);
    sh_ze[r] = z;
  }
  __syncthreads();

  // VQ: argmin_k ||e_k||^2 - 2 z_e . e_k
  float best = INFINITY; int bi = 0;
  for (int k = r; k < NCODES; k += 512) {
    float d = 0.f;
#pragma unroll
    for (int q = 0; q < LATENT / 4; ++q) {
      float4 e = *(const float4*)&emb[(size_t)k * LATENT + q * 4];
      float4 z = *(const float4*)&sh_ze[q * 4];
      d += e.x * (e.x - 2.f * z.x) + e.y * (e.y - 2.f * z.y)
         + e.z * (e.z - 2.f * z.z) + e.w * (e.w - 2.f * z.w);
    }
    if (d < best) { best = d; bi = k; }
  }
  sh_rd[r] = best; sh_ri[r] = bi;
  __syncthreads();
  for (int s = 256; s > 0; s >>= 1) {
    if (r < s) {
      float od = sh_rd[r + s]; int oi = sh_ri[r + s];
      if (od < sh_rd[r] || (od == sh_rd[r] && oi < sh_ri[r])) { sh_rd[r] = od; sh_ri[r] = oi; }
    }
    __syncthreads();
  }
  const int kmin = sh_ri[0];
  if (r < LATENT) sh_zq[r] = emb[(size_t)kmin * LATENT + r];
  __syncthreads();

  // p1[b][j] = b1 + W1[:,0:128].zq + W1[:,1664:2432].noise  (pad cols 200..255 = 0)
  if (r < 256) {
    float v = 0.f;
    if (r < HID) {
      v = b1[r];
      const float* wrow = W1 + (size_t)r * 2432;
#pragma unroll 4
      for (int d = 0; d < LATENT; ++d) v = fmaf(wrow[d], sh_zq[d], v);
      const float* nz = noise + (size_t)b * DIN;
#pragma unroll 4
      for (int d = 0; d < DIN; ++d) v = fmaf(wrow[1664 + d], nz[d], v);
    }
    p1[b * 256 + r] = v;
  }
}

// ---------------- host ----------------
extern "C" void kernel_launch(void* const* d_in, const int* in_sizes, int n_in,
                              void* d_out, int out_size, void* d_ws, size_t ws_size,
                              hipStream_t stream) {
  const float* x     = (const float*)d_in[0];
  const float* cond  = (const float*)d_in[1];
  const float* noise = (const float*)d_in[2];
  const float* W_ih  = (const float*)d_in[3];
  const float* W_hh  = (const float*)d_in[4];
  const float* b_ih  = (const float*)d_in[5];
  const float* b_hh  = (const float*)d_in[6];
  const float* W_enc = (const float*)d_in[7];
  const float* b_enc = (const float*)d_in[8];
  const float* emb   = (const float*)d_in[9];
  const float* W1    = (const float*)d_in[10];
  const float* b1    = (const float*)d_in[11];
  const float* W2    = (const float*)d_in[12];
  const float* b2    = (const float*)d_in[13];
  const float* W3    = (const float*)d_in[14];
  const float* b3    = (const float*)d_in[15];

  char* ws = (char*)d_ws;
  size_t off = 0;
  auto alloc = [&](size_t bytes) -> void* {
    void* p = ws + off; off += (bytes + 255) & ~(size_t)255; return p;
  };
  u16*      W_ihb = (u16*)alloc((size_t)896 * 768 * 2);
  u16*      W1cb  = (u16*)alloc((size_t)256 * 1536 * 2);
  u16*      W2b   = (u16*)alloc((size_t)512 * 256 * 2);
  u16*      W3b   = (u16*)alloc((size_t)768 * 512 * 2);
  float*    b2p   = (float*)alloc(512 * 4);
  unsigned* W4    = (unsigned*)alloc((size_t)W4_BYTES);
  unsigned* Wreg  = (unsigned*)alloc((size_t)200 * 8 * 4);
  float*    biasc = (float*)alloc(LDG * 4);
  u16*      gates = (u16*)alloc((size_t)MROWS * LDG * 2);
  float*    p1    = (float*)alloc(256 * 256 * 4);
  u16*      h1    = (u16*)alloc((size_t)MROWS * LDH1 * 2);
  u16*      h2    = (u16*)alloc((size_t)MROWS * LDH2 * 2);

  cvt_pad<<<dim3((896 * 768 + 255) / 256), 256, 0, stream>>>(W_ih, W_ihb, 800, 768, 768, 0, 896, 768);
  cvt_pad<<<dim3((256 * 1536 + 255) / 256), 256, 0, stream>>>(W1, W1cb, 200, 1536, 2432, 128, 256, 1536);
  cvt_pad<<<dim3((512 * 256 + 255) / 256), 256, 0, stream>>>(W2, W2b, 400, 200, 200, 0, 512, 256);
  cvt_pad<<<dim3((768 * 512 + 255) / 256), 256, 0, stream>>>(W3, W3b, 768, 400, 400, 0, 768, 512);
  pad_f32<<<dim3(2), 256, 0, stream>>>(b2, b2p, 400, 512);
  pack_whh_i8<<<dim3((800 * 50 + 255) / 256), 256, 0, stream>>>(W_hh, W4, Wreg, b_ih, b_hh, biasc);

  // gates = x @ W_ih^T + (b_ih + b_hh), bf16 out, ld 896
  gemm_bf16<true, EPI_GATES><<<dim3(LDG / 128, MROWS / 128), 256, 0, stream>>>(
      x, W_ihb, gates, 768, LDG, biasc);

  // LSTM scan + encoder + VQ + p1 (W_hh in dynamic LDS, i8; 512 thr k-split)
  static bool attr_set = false;
  if (!attr_set) {
    (void)hipFuncSetAttribute((const void*)lstm_enc,
                              hipFuncAttributeMaxDynamicSharedMemorySize, W4_BYTES);
    attr_set = true;
  }
  lstm_enc<<<dim3(NB), 512, W4_BYTES, stream>>>(gates, (const uint4*)W4, (const uint4*)Wreg,
                                                W_enc, b_enc, emb, W1, b1, noise, p1);

  // h1 = relu(cond @ W1c^T + p1[b])
  gemm_bf16<true, EPI_H1><<<dim3(LDH1 / 128, MROWS / 128), 256, 0, stream>>>(
      cond, W1cb, h1, DCOND, LDH1, p1);
  // h2 = relu(h1 @ W2^T + b2)
  gemm_bf16<false, EPI_H2><<<dim3(LDH2 / 128, MROWS / 128), 256, 0, stream>>>(
      h1, W2b, h2, LDH1, LDH2, b2p);
  // out = sigmoid(h2 @ W3^T + b3)
  gemm_bf16<false, EPI_OUT><<<dim3(NOUT / 128, MROWS / 128), 256, 0, stream>>>(
      h2, W3b, (float*)d_out, LDH2, NOUT, b3);
}

// Round 16
// 507.252 us; speedup vs baseline: 2.5041x; 1.0337x over previous
//
#include <hip/hip_runtime.h>
#include <math.h>

typedef unsigned short u16;
typedef u16 u16x8 __attribute__((ext_vector_type(8)));
typedef __bf16 bf16x8 __attribute__((ext_vector_type(8)));
typedef float f32x4 __attribute__((ext_vector_type(4)));

#define HID 200
#define G4H 800
#define TLEN 128
#define LATENT 128
#define NCODES 1024
#define DIN 768
#define DCOND 1536
#define NB 256
#define MROWS (NB * TLEN)
#define LDG 896
#define LDH1 256
#define LDH2 512
#define NOUT 768

#define WSCL 400.0f
#define HSCL 127.0f
#define ISCL (1.0f / (WSCL * HSCL))
#define W4_UINT4 (12 * 800)          // k 0..191, i8-packed, [jb][row] uint4
#define W4_BYTES (W4_UINT4 * 16)     // 153600
#define NTHR 640

__device__ __forceinline__ u16 f2b(float f) {
  union { float f; unsigned u; } v; v.f = f;
  unsigned r = v.u + 0x7fffu + ((v.u >> 16) & 1u);
  return (u16)(r >> 16);
}
__device__ __forceinline__ float b2f(u16 h) {
  union { unsigned u; float f; } v; v.u = ((unsigned)h) << 16;
  return v.f;
}
__device__ __forceinline__ float sigf(float x) { return 1.f / (1.f + __expf(-x)); }
__device__ __forceinline__ float tanh_fast(float x) {
  return 1.f - 2.f / (__expf(2.f * x) + 1.f);
}

__device__ __forceinline__ int dot4(unsigned a, unsigned b, int c) {
#if __has_builtin(__builtin_amdgcn_sdot4)
  return __builtin_amdgcn_sdot4((int)a, (int)b, c, false);
#else
  int s = c;
  s += (int)(signed char)(a) * (int)(signed char)(b);
  s += (int)(signed char)(a >> 8) * (int)(signed char)(b >> 8);
  s += (int)(signed char)(a >> 16) * (int)(signed char)(b >> 16);
  s += (int)(signed char)(a >> 24) * (int)(signed char)(b >> 24);
  return s;
#endif
}

// async global->LDS, 16B per lane
__device__ __forceinline__ void gl16(const void* g, void* l) {
  __builtin_amdgcn_global_load_lds(
      (const __attribute__((address_space(1))) void*)g,
      (__attribute__((address_space(3))) void*)l, 16, 0, 0);
}

__device__ __forceinline__ unsigned cvtpk(float a, float b) {
  unsigned r;
  asm("v_cvt_pk_bf16_f32 %0, %1, %2" : "=v"(r) : "v"(a), "v"(b));
  return r;
}

// ---------------- weight convert + pad ----------------
__global__ void cvt_pad(const float* __restrict__ src, u16* __restrict__ dst,
                        int nr, int nc, int lds, int col0, int NRp, int KP) {
  int i = blockIdx.x * blockDim.x + threadIdx.x;
  if (i >= NRp * KP) return;
  int r = i / KP, c = i - r * KP;
  float v = (r < nr && c < nc) ? src[(size_t)r * lds + col0 + c] : 0.f;
  dst[i] = f2b(v);
}

__global__ void pad_f32(const float* __restrict__ src, float* __restrict__ dst,
                        int n, int npad) {
  int i = blockIdx.x * blockDim.x + threadIdx.x;
  if (i < npad) dst[i] = (i < n) ? src[i] : 0.f;
}

// W_hh [800][200] f32 -> i8 (x400 scale):
//   k 0..191  -> W4 dword index (jb*800 + row)*4 + word   (uint4 per [jb][row])
//   k 192..199-> Wreg[u*8 + g*2 + d] for row = g*200+u
// biasc[col<896] = b_ih+b_hh (0-padded) for the gates-GEMM epilogue.
__global__ void pack_whh_i8(const float* __restrict__ Whh, unsigned* __restrict__ W4,
                            unsigned* __restrict__ Wreg,
                            const float* __restrict__ b_ih, const float* __restrict__ b_hh,
                            float* __restrict__ biasc) {
  int i = blockIdx.x * blockDim.x + threadIdx.x;
  if (i < 800 * 50) {
    int row = i / 50, dw = i - row * 50;
    unsigned d = 0;
#pragma unroll
    for (int e = 0; e < 4; ++e) {
      int k = dw * 4 + e;
      float w = Whh[(size_t)row * HID + k] * WSCL;
      int q = (int)lrintf(w);
      q = q > 127 ? 127 : (q < -127 ? -127 : q);
      d |= ((unsigned)(q & 0xFF)) << (8 * e);
    }
    if (dw < 48) {
      W4[((dw >> 2) * 800 + row) * 4 + (dw & 3)] = d;
    } else {  // dw in {48,49}: k 192..199
      int g = row / 200, u = row - g * 200;
      Wreg[u * 8 + g * 2 + (dw - 48)] = d;
    }
  }
  if (i < LDG) biasc[i] = (i < G4H) ? (b_ih[i] + b_hh[i]) : 0.f;
}

// ---------------- bf16 MFMA GEMM: C[M,N] = A[M,K] * B[N,K]^T (+epilogue) ----------------
enum { EPI_GATES = 0, EPI_H1 = 1, EPI_H2 = 2, EPI_OUT = 3 };

__device__ __forceinline__ f32x4 mfma16(bf16x8 a, bf16x8 b, f32x4 c) {
  return __builtin_amdgcn_mfma_f32_16x16x32_bf16(a, b, c, 0, 0, 0);
}

template<bool AF32, int EPI>
__global__ __launch_bounds__(256) void gemm_bf16(
    const void* __restrict__ Ap, const u16* __restrict__ Bp,
    void* __restrict__ Cp, int K, int ldc, const float* __restrict__ bias) {
  __shared__ __attribute__((aligned(16))) char AsRaw[AF32 ? 128 * 32 * 4 : 128 * 32 * 2];
  __shared__ __attribute__((aligned(16))) u16 Bs[128 * 32];
  float* Asf = (float*)AsRaw;
  u16* As16 = (u16*)AsRaw;

  const int t = threadIdx.x;
  const int tileN = blockIdx.x * 128;
  const int tileM = blockIdx.y * 128;
  const int l = t & 63;
  const int w = t >> 6;
  const int wr = (w >> 1) * 64;
  const int wc = (w & 1) * 64;
  const int fr = l & 15;
  const int fg = l >> 4;

  const u16* bsrc[2];
  u16* bdst[2];
#pragma unroll
  for (int j = 0; j < 2; ++j) {
    int tb = w * 1024 + j * 4096 + (t & 63) * 16;
    int row = tb >> 6, gd = (tb >> 4) & 3;
    bsrc[j] = Bp + (size_t)(tileN + row) * K + ((gd ^ ((row >> 1) & 3)) << 3);
    bdst[j] = Bs + w * 512 + j * 2048;
  }
  const float* asrcF[4];
  float* adstF[4];
  const u16* asrcH[2];
  u16* adstH[2];
  if constexpr (AF32) {
#pragma unroll
    for (int j = 0; j < 4; ++j) {
      int tb = w * 1024 + j * 4096 + (t & 63) * 16;
      int row = tb >> 7, gd = (tb >> 4) & 7;
      asrcF[j] = (const float*)Ap + (size_t)(tileM + row) * K + ((gd ^ (row & 7)) << 2);
      adstF[j] = Asf + w * 256 + j * 1024;
    }
  } else {
#pragma unroll
    for (int j = 0; j < 2; ++j) {
      int tb = w * 1024 + j * 4096 + (t & 63) * 16;
      int row = tb >> 6, gd = (tb >> 4) & 3;
      asrcH[j] = (const u16*)Ap + (size_t)(tileM + row) * K + ((gd ^ ((row >> 1) & 3)) << 3);
      adstH[j] = As16 + w * 512 + j * 2048;
    }
  }

  f32x4 acc[4][4];
#pragma unroll
  for (int m = 0; m < 4; ++m)
#pragma unroll
    for (int n = 0; n < 4; ++n) {
      f32x4 z = {0.f, 0.f, 0.f, 0.f};
      acc[m][n] = z;
    }

  for (int k0 = 0; k0 < K; k0 += 32) {
#pragma unroll
    for (int j = 0; j < 2; ++j) { gl16(bsrc[j], bdst[j]); bsrc[j] += 32; }
    if constexpr (AF32) {
#pragma unroll
      for (int j = 0; j < 4; ++j) { gl16(asrcF[j], adstF[j]); asrcF[j] += 32; }
    } else {
#pragma unroll
      for (int j = 0; j < 2; ++j) { gl16(asrcH[j], adstH[j]); asrcH[j] += 32; }
    }
    __syncthreads();

    bf16x8 av[4], bv[4];
#pragma unroll
    for (int m = 0; m < 4; ++m) {
      const int row = wr + m * 16 + fr;
      if constexpr (AF32) {
        const int g0 = (2 * fg) ^ (row & 7);
        const int g1 = (2 * fg + 1) ^ (row & 7);
        float4 p0 = *(const float4*)(Asf + row * 32 + g0 * 4);
        float4 p1 = *(const float4*)(Asf + row * 32 + g1 * 4);
        uint4 u;
        u.x = cvtpk(p0.x, p0.y); u.y = cvtpk(p0.z, p0.w);
        u.z = cvtpk(p1.x, p1.y); u.w = cvtpk(p1.z, p1.w);
        av[m] = __builtin_bit_cast(bf16x8, u);
      } else {
        const int g = fg ^ ((row >> 1) & 3);
        av[m] = __builtin_bit_cast(bf16x8, *(const u16x8*)(As16 + row * 32 + g * 8));
      }
    }
#pragma unroll
    for (int n = 0; n < 4; ++n) {
      const int row = wc + n * 16 + fr;
      const int g = fg ^ ((row >> 1) & 3);
      bv[n] = __builtin_bit_cast(bf16x8, *(const u16x8*)(Bs + row * 32 + g * 8));
    }
#pragma unroll
    for (int m = 0; m < 4; ++m)
#pragma unroll
      for (int n = 0; n < 4; ++n)
        acc[m][n] = mfma16(av[m], bv[n], acc[m][n]);
    __syncthreads();
  }

#pragma unroll
  for (int m = 0; m < 4; ++m) {
#pragma unroll
    for (int n = 0; n < 4; ++n) {
      const int gcol = tileN + wc + n * 16 + fr;
      const int growb = tileM + wr + m * 16 + fg * 4;
#pragma unroll
      for (int r = 0; r < 4; ++r) {
        const int grow = growb + r;
        float v = acc[m][n][r];
        if constexpr (EPI == EPI_GATES) {
          v += bias[gcol];   // b_ih + b_hh folded here
          ((u16*)Cp)[(size_t)grow * ldc + gcol] = f2b(v);
        } else if constexpr (EPI == EPI_H1) {
          v += bias[(grow >> 7) * 256 + gcol];
          v = fmaxf(v, 0.f);
          ((u16*)Cp)[(size_t)grow * ldc + gcol] = f2b(v);
        } else if constexpr (EPI == EPI_H2) {
          v += bias[gcol];
          v = fmaxf(v, 0.f);
          ((u16*)Cp)[(size_t)grow * ldc + gcol] = f2b(v);
        } else {
          v += bias[gcol];
          ((float*)Cp)[(size_t)grow * ldc + gcol] = sigf(v);
        }
      }
    }
  }
}

// ---------------- fused LSTM scan + encoder + VQ + p1 ----------------
// 640 threads (10 waves ~ 2.5/SIMD), one block per batch. W_hh i8 in LDS
// ([jb][row] uint4, conflict-free) + tail dwords in kh2 regs. 3-WAY K-SPLIT:
// worker r<600 = (u = r%200, kh = r/200); kh covers jb [4kh, 4kh+4) (k 64*kh..);
// kh2 also does the k192..199 tail. kh1/kh2 write uint4 partials [u][g]
// (conflict-free b128); kh0 adds + activation (worker-local) + h-write.
// Same integer math as R14/R15 -> bit-identical result.
__global__ __launch_bounds__(NTHR) void lstm_enc(
    const u16* __restrict__ gates, const uint4* __restrict__ W4g,
    const uint4* __restrict__ WregG,
    const float* __restrict__ Wenc, const float* __restrict__ b_enc,
    const float* __restrict__ emb, const float* __restrict__ W1,
    const float* __restrict__ b1, const float* __restrict__ noise,
    float* __restrict__ p1) {
  extern __shared__ __attribute__((aligned(16))) char dynsm[];
  uint4* W4 = (uint4*)dynsm;                       // [12*800] uint4 (i8)
  __shared__ __attribute__((aligned(16))) unsigned sh_hq[2][56];  // h i8, dbuf, pad 0
  __shared__ __attribute__((aligned(16))) char sh_un[2 * 208 * 16];  // sh_p / rd+ri
  __shared__ __attribute__((aligned(16))) float sh_hf[HID];
  __shared__ __attribute__((aligned(16))) float sh_ze[LATENT];
  __shared__ float sh_zq[LATENT];
  int (*sh_p)[208][4] = (int(*)[208][4])sh_un;   // [2][208][4]
  float* sh_rd = (float*)sh_un;                  // [640]
  int* sh_ri = (int*)(sh_un + NTHR * 4);         // [640]
  const int r = threadIdx.x;
  const int b = blockIdx.x;
  const bool act = (r < 600);
  const int kh = r / 200;          // 0,1,2 (3 for idle tail)
  const int u = r - kh * 200;
  const bool lo = (kh == 0);

  // stage W4 into LDS (9600 uint4, coalesced; L2-resident source)
  for (int i = r; i < W4_UINT4; i += NTHR) W4[i] = W4g[i];
  uint4 wt0 = {0, 0, 0, 0}, wt1 = {0, 0, 0, 0};
  if (kh == 2) { wt0 = WregG[u * 2]; wt1 = WregG[u * 2 + 1]; }
  if (r < 56) { sh_hq[0][r] = 0; sh_hq[1][r] = 0; }
  float c = 0.f, hlast = 0.f;
  const u16* gp = gates + (size_t)b * TLEN * LDG + u;
  float gv0 = 0.f, gv1 = 0.f, gv2 = 0.f, gv3 = 0.f;
  if (lo) {
    gv0 = b2f(gp[0]); gv1 = b2f(gp[200]);
    gv2 = b2f(gp[400]); gv3 = b2f(gp[600]);
  }
  __syncthreads();

  for (int t = 0; t < TLEN; ++t) {
    gp += LDG;
    float gn0 = 0.f, gn1 = 0.f, gn2 = 0.f, gn3 = 0.f;
    if (lo && t + 1 < TLEN) {
      gn0 = b2f(gp[0]); gn1 = b2f(gp[200]);
      gn2 = b2f(gp[400]); gn3 = b2f(gp[600]);
    }
    const int cur = t & 1, nxt = cur ^ 1;

    int a0 = 0, a1 = 0, a2 = 0, a3 = 0;
    if (act) {
      unsigned hd[16];
#pragma unroll
      for (int j = 0; j < 4; ++j) {
        uint4 v = ((const uint4*)sh_hq[cur])[kh * 4 + j];
        hd[4 * j + 0] = v.x; hd[4 * j + 1] = v.y;
        hd[4 * j + 2] = v.z; hd[4 * j + 3] = v.w;
      }
#pragma unroll
      for (int j = 0; j < 4; ++j) {
        const int jb = kh * 4 + j;
        uint4 w0 = W4[jb * 800 + u];
        uint4 w1 = W4[jb * 800 + 200 + u];
        uint4 w2 = W4[jb * 800 + 400 + u];
        uint4 w3 = W4[jb * 800 + 600 + u];
#pragma unroll
        for (int e = 0; e < 4; ++e) {
          unsigned h = hd[j * 4 + e];
          a0 = dot4((&w0.x)[e], h, a0);
          a1 = dot4((&w1.x)[e], h, a1);
          a2 = dot4((&w2.x)[e], h, a2);
          a3 = dot4((&w3.x)[e], h, a3);
        }
      }
      if (kh == 2) {
        // tail k 192..199 from registers
        uint2 ht = *(const uint2*)&sh_hq[cur][48];
        a0 = dot4(wt0.x, ht.x, a0); a0 = dot4(wt0.y, ht.y, a0);
        a1 = dot4(wt0.z, ht.x, a1); a1 = dot4(wt0.w, ht.y, a1);
        a2 = dot4(wt1.x, ht.x, a2); a2 = dot4(wt1.y, ht.y, a2);
        a3 = dot4(wt1.z, ht.x, a3); a3 = dot4(wt1.w, ht.y, a3);
      }
      if (kh) {
        int4 pv; pv.x = a0; pv.y = a1; pv.z = a2; pv.w = a3;
        *(int4*)&sh_p[kh - 1][u][0] = pv;
      }
    }
    __syncthreads();   // partials visible
    if (lo) {
      int4 p0 = *(const int4*)&sh_p[0][u][0];
      int4 p1v = *(const int4*)&sh_p[1][u][0];
      float gi = gv0 + (float)(a0 + p0.x + p1v.x) * ISCL;
      float gf = gv1 + (float)(a1 + p0.y + p1v.y) * ISCL;
      float gg = gv2 + (float)(a2 + p0.z + p1v.z) * ISCL;
      float go = gv3 + (float)(a3 + p0.w + p1v.w) * ISCL;
      c = sigf(gf) * c + sigf(gi) * tanh_fast(gg);
      hlast = sigf(go) * tanh_fast(c);
      ((char*)sh_hq[nxt])[u] = (char)__float2int_rn(hlast * HSCL);
    }
    __syncthreads();   // h(t+1) visible; sh_p free for reuse
    gv0 = gn0; gv1 = gn1; gv2 = gn2; gv3 = gn3;
  }

  if (lo) sh_hf[u] = hlast;
  __syncthreads();

  // encoder: z_e = h @ Wenc^T + b_enc
  if (r < LATENT) {
    float z = b_enc[r];
#pragma unroll 4
    for (int k = 0; k < HID; ++k) z = fmaf(Wenc[(size_t)r * HID + k], sh_hf[k], z);
    sh_ze[r] = z;
  }
  __syncthreads();

  // VQ: argmin_k ||e_k||^2 - 2 z_e . e_k
  float best = INFINITY; int bi = 0;
  for (int k = r; k < NCODES; k += NTHR) {
    float d = 0.f;
#pragma unroll
    for (int q = 0; q < LATENT / 4; ++q) {
      float4 e = *(const float4*)&emb[(size_t)k * LATENT + q * 4];
      float4 z = *(const float4*)&sh_ze[q * 4];
      d += e.x * (e.x - 2.f * z.x) + e.y * (e.y - 2.f * z.y)
         + e.z * (e.z - 2.f * z.z) + e.w * (e.w - 2.f * z.w);
    }
    if (d < best) { best = d; bi = k; }
  }
  sh_rd[r] = best; sh_ri[r] = bi;
  __syncthreads();
  for (int s = 512; s > 0; s >>= 1) {
    if (r < s && r + s < NTHR) {
      float od = sh_rd[r + s]; int oi = sh_ri[r + s];
      if (od < sh_rd[r] || (od == sh_rd[r] && oi < sh_ri[r])) { sh_rd[r] = od; sh_ri[r] = oi; }
    }
    __syncthreads();
  }
  const int kmin = sh_ri[0];
  if (r < LATENT) sh_zq[r] = emb[(size_t)kmin * LATENT + r];
  __syncthreads();

  // p1[b][j] = b1 + W1[:,0:128].zq + W1[:,1664:2432].noise  (pad cols 200..255 = 0)
  if (r < 256) {
    float v = 0.f;
    if (r < HID) {
      v = b1[r];
      const float* wrow = W1 + (size_t)r * 2432;
#pragma unroll 4
      for (int d = 0; d < LATENT; ++d) v = fmaf(wrow[d], sh_zq[d], v);
      const float* nz = noise + (size_t)b * DIN;
#pragma unroll 4
      for (int d = 0; d < DIN; ++d) v = fmaf(wrow[1664 + d], nz[d], v);
    }
    p1[b * 256 + r] = v;
  }
}

// ---------------- host ----------------
extern "C" void kernel_launch(void* const* d_in, const int* in_sizes, int n_in,
                              void* d_out, int out_size, void* d_ws, size_t ws_size,
                              hipStream_t stream) {
  const float* x     = (const float*)d_in[0];
  const float* cond  = (const float*)d_in[1];
  const float* noise = (const float*)d_in[2];
  const float* W_ih  = (const float*)d_in[3];
  const float* W_hh  = (const float*)d_in[4];
  const float* b_ih  = (const float*)d_in[5];
  const float* b_hh  = (const float*)d_in[6];
  const float* W_enc = (const float*)d_in[7];
  const float* b_enc = (const float*)d_in[8];
  const float* emb   = (const float*)d_in[9];
  const float* W1    = (const float*)d_in[10];
  const float* b1    = (const float*)d_in[11];
  const float* W2    = (const float*)d_in[12];
  const float* b2    = (const float*)d_in[13];
  const float* W3    = (const float*)d_in[14];
  const float* b3    = (const float*)d_in[15];

  char* ws = (char*)d_ws;
  size_t off = 0;
  auto alloc = [&](size_t bytes) -> void* {
    void* p = ws + off; off += (bytes + 255) & ~(size_t)255; return p;
  };
  u16*      W_ihb = (u16*)alloc((size_t)896 * 768 * 2);
  u16*      W1cb  = (u16*)alloc((size_t)256 * 1536 * 2);
  u16*      W2b   = (u16*)alloc((size_t)512 * 256 * 2);
  u16*      W3b   = (u16*)alloc((size_t)768 * 512 * 2);
  float*    b2p   = (float*)alloc(512 * 4);
  unsigned* W4    = (unsigned*)alloc((size_t)W4_BYTES);
  unsigned* Wreg  = (unsigned*)alloc((size_t)200 * 8 * 4);
  float*    biasc = (float*)alloc(LDG * 4);
  u16*      gates = (u16*)alloc((size_t)MROWS * LDG * 2);
  float*    p1    = (float*)alloc(256 * 256 * 4);
  u16*      h1    = (u16*)alloc((size_t)MROWS * LDH1 * 2);
  u16*      h2    = (u16*)alloc((size_t)MROWS * LDH2 * 2);

  cvt_pad<<<dim3((896 * 768 + 255) / 256), 256, 0, stream>>>(W_ih, W_ihb, 800, 768, 768, 0, 896, 768);
  cvt_pad<<<dim3((256 * 1536 + 255) / 256), 256, 0, stream>>>(W1, W1cb, 200, 1536, 2432, 128, 256, 1536);
  cvt_pad<<<dim3((512 * 256 + 255) / 256), 256, 0, stream>>>(W2, W2b, 400, 200, 200, 0, 512, 256);
  cvt_pad<<<dim3((768 * 512 + 255) / 256), 256, 0, stream>>>(W3, W3b, 768, 400, 400, 0, 768, 512);
  pad_f32<<<dim3(2), 256, 0, stream>>>(b2, b2p, 400, 512);
  pack_whh_i8<<<dim3((800 * 50 + 255) / 256), 256, 0, stream>>>(W_hh, W4, Wreg, b_ih, b_hh, biasc);

  // gates = x @ W_ih^T + (b_ih + b_hh), bf16 out, ld 896
  gemm_bf16<true, EPI_GATES><<<dim3(LDG / 128, MROWS / 128), 256, 0, stream>>>(
      x, W_ihb, gates, 768, LDG, biasc);

  // LSTM scan + encoder + VQ + p1 (W_hh in dynamic LDS, i8; 640 thr, 3-way k-split)
  static bool attr_set = false;
  if (!attr_set) {
    (void)hipFuncSetAttribute((const void*)lstm_enc,
                              hipFuncAttributeMaxDynamicSharedMemorySize, W4_BYTES);
    attr_set = true;
  }
  lstm_enc<<<dim3(NB), NTHR, W4_BYTES, stream>>>(gates, (const uint4*)W4, (const uint4*)Wreg,
                                                 W_enc, b_enc, emb, W1, b1, noise, p1);

  // h1 = relu(cond @ W1c^T + p1[b])
  gemm_bf16<true, EPI_H1><<<dim3(LDH1 / 128, MROWS / 128), 256, 0, stream>>>(
      cond, W1cb, h1, DCOND, LDH1, p1);
  // h2 = relu(h1 @ W2^T + b2)
  gemm_bf16<false, EPI_H2><<<dim3(LDH2 / 128, MROWS / 128), 256, 0, stream>>>(
      h1, W2b, h2, LDH1, LDH2, b2p);
  // out = sigmoid(h2 @ W3^T + b3)
  gemm_bf16<false, EPI_OUT><<<dim3(NOUT / 128, MROWS / 128), 256, 0, stream>>>(
      h2, W3b, (float*)d_out, LDH2, NOUT, b3);
}

// Round 17
// 477.600 us; speedup vs baseline: 2.6596x; 1.0621x over previous
//
#include <hip/hip_runtime.h>
#include <math.h>

typedef unsigned short u16;
typedef u16 u16x8 __attribute__((ext_vector_type(8)));
typedef __bf16 bf16x8 __attribute__((ext_vector_type(8)));
typedef float f32x4 __attribute__((ext_vector_type(4)));

#define HID 200
#define G4H 800
#define TLEN 128
#define LATENT 128
#define NCODES 1024
#define DIN 768
#define DCOND 1536
#define NB 256
#define MROWS (NB * TLEN)
#define LDG 896
#define LDH1 256
#define LDH2 512
#define NOUT 768

#define WSCL 400.0f
#define HSCL 127.0f
#define ISCL (1.0f / (WSCL * HSCL))
#define W4_UINT4 (12 * 800)          // k 0..191, i8-packed, [jb][row] uint4
#define W4_BYTES (W4_UINT4 * 16)     // 153600
#define NTHR 640

__device__ __forceinline__ u16 f2b(float f) {
  union { float f; unsigned u; } v; v.f = f;
  unsigned r = v.u + 0x7fffu + ((v.u >> 16) & 1u);
  return (u16)(r >> 16);
}
__device__ __forceinline__ float b2f(u16 h) {
  union { unsigned u; float f; } v; v.u = ((unsigned)h) << 16;
  return v.f;
}
__device__ __forceinline__ float sigf(float x) { return 1.f / (1.f + __expf(-x)); }
__device__ __forceinline__ float tanh_fast(float x) {
  return 1.f - 2.f / (__expf(2.f * x) + 1.f);
}

__device__ __forceinline__ int dot4(unsigned a, unsigned b, int c) {
#if __has_builtin(__builtin_amdgcn_sdot4)
  return __builtin_amdgcn_sdot4((int)a, (int)b, c, false);
#else
  int s = c;
  s += (int)(signed char)(a) * (int)(signed char)(b);
  s += (int)(signed char)(a >> 8) * (int)(signed char)(b >> 8);
  s += (int)(signed char)(a >> 16) * (int)(signed char)(b >> 16);
  s += (int)(signed char)(a >> 24) * (int)(signed char)(b >> 24);
  return s;
#endif
}

// async global->LDS, 16B per lane
__device__ __forceinline__ void gl16(const void* g, void* l) {
  __builtin_amdgcn_global_load_lds(
      (const __attribute__((address_space(1))) void*)g,
      (__attribute__((address_space(3))) void*)l, 16, 0, 0);
}

__device__ __forceinline__ unsigned cvtpk(float a, float b) {
  unsigned r;
  asm("v_cvt_pk_bf16_f32 %0, %1, %2" : "=v"(r) : "v"(a), "v"(b));
  return r;
}

// LDS-ordering-only barrier: global prefetch loads stay in flight (no vmcnt drain)
__device__ __forceinline__ void bar_lds() {
  asm volatile("s_waitcnt lgkmcnt(0)\n\ts_barrier" ::: "memory");
}

// ---------------- weight convert + pad ----------------
__global__ void cvt_pad(const float* __restrict__ src, u16* __restrict__ dst,
                        int nr, int nc, int lds, int col0, int NRp, int KP) {
  int i = blockIdx.x * blockDim.x + threadIdx.x;
  if (i >= NRp * KP) return;
  int r = i / KP, c = i - r * KP;
  float v = (r < nr && c < nc) ? src[(size_t)r * lds + col0 + c] : 0.f;
  dst[i] = f2b(v);
}

__global__ void pad_f32(const float* __restrict__ src, float* __restrict__ dst,
                        int n, int npad) {
  int i = blockIdx.x * blockDim.x + threadIdx.x;
  if (i < npad) dst[i] = (i < n) ? src[i] : 0.f;
}

// W_hh [800][200] f32 -> i8 (x400 scale):
//   k 0..191  -> W4 dword index (jb*800 + row)*4 + word   (uint4 per [jb][row])
//   k 192..199-> Wreg[u*8 + g*2 + d] for row = g*200+u
// biasc[col<896] = b_ih+b_hh (0-padded) for the gates-GEMM epilogue.
__global__ void pack_whh_i8(const float* __restrict__ Whh, unsigned* __restrict__ W4,
                            unsigned* __restrict__ Wreg,
                            const float* __restrict__ b_ih, const float* __restrict__ b_hh,
                            float* __restrict__ biasc) {
  int i = blockIdx.x * blockDim.x + threadIdx.x;
  if (i < 800 * 50) {
    int row = i / 50, dw = i - row * 50;
    unsigned d = 0;
#pragma unroll
    for (int e = 0; e < 4; ++e) {
      int k = dw * 4 + e;
      float w = Whh[(size_t)row * HID + k] * WSCL;
      int q = (int)lrintf(w);
      q = q > 127 ? 127 : (q < -127 ? -127 : q);
      d |= ((unsigned)(q & 0xFF)) << (8 * e);
    }
    if (dw < 48) {
      W4[((dw >> 2) * 800 + row) * 4 + (dw & 3)] = d;
    } else {  // dw in {48,49}: k 192..199
      int g = row / 200, u = row - g * 200;
      Wreg[u * 8 + g * 2 + (dw - 48)] = d;
    }
  }
  if (i < LDG) biasc[i] = (i < G4H) ? (b_ih[i] + b_hh[i]) : 0.f;
}

// ---------------- bf16 MFMA GEMM: C[M,N] = A[M,K] * B[N,K]^T (+epilogue) ----------------
// 1D grid + chunked XCD swizzle (T1, m157; requires nwg % 8 == 0 -- all our
// grids are): logical id = (bid&7)*(nwg/8) + (bid>>3); x-major tile mapping so
// same-M-panel blocks (sharing the A tile) land on the same XCD's L2.
enum { EPI_GATES = 0, EPI_H1 = 1, EPI_H2 = 2, EPI_OUT = 3 };

__device__ __forceinline__ f32x4 mfma16(bf16x8 a, bf16x8 b, f32x4 c) {
  return __builtin_amdgcn_mfma_f32_16x16x32_bf16(a, b, c, 0, 0, 0);
}

template<bool AF32, int EPI>
__global__ __launch_bounds__(256) void gemm_bf16(
    const void* __restrict__ Ap, const u16* __restrict__ Bp,
    void* __restrict__ Cp, int K, int ldc, const float* __restrict__ bias, int nx) {
  __shared__ __attribute__((aligned(16))) char AsRaw[AF32 ? 128 * 32 * 4 : 128 * 32 * 2];
  __shared__ __attribute__((aligned(16))) u16 Bs[128 * 32];
  float* Asf = (float*)AsRaw;
  u16* As16 = (u16*)AsRaw;

  const int t = threadIdx.x;
  const int nwg = gridDim.x;
  const int bid = blockIdx.x;
  const int lid = (bid & 7) * (nwg >> 3) + (bid >> 3);   // chunked XCD swizzle
  const int tileN = (lid % nx) * 128;
  const int tileM = (lid / nx) * 128;
  const int l = t & 63;
  const int w = t >> 6;
  const int wr = (w >> 1) * 64;
  const int wc = (w & 1) * 64;
  const int fr = l & 15;
  const int fg = l >> 4;

  const u16* bsrc[2];
  u16* bdst[2];
#pragma unroll
  for (int j = 0; j < 2; ++j) {
    int tb = w * 1024 + j * 4096 + (t & 63) * 16;
    int row = tb >> 6, gd = (tb >> 4) & 3;
    bsrc[j] = Bp + (size_t)(tileN + row) * K + ((gd ^ ((row >> 1) & 3)) << 3);
    bdst[j] = Bs + w * 512 + j * 2048;
  }
  const float* asrcF[4];
  float* adstF[4];
  const u16* asrcH[2];
  u16* adstH[2];
  if constexpr (AF32) {
#pragma unroll
    for (int j = 0; j < 4; ++j) {
      int tb = w * 1024 + j * 4096 + (t & 63) * 16;
      int row = tb >> 7, gd = (tb >> 4) & 7;
      asrcF[j] = (const float*)Ap + (size_t)(tileM + row) * K + ((gd ^ (row & 7)) << 2);
      adstF[j] = Asf + w * 256 + j * 1024;
    }
  } else {
#pragma unroll
    for (int j = 0; j < 2; ++j) {
      int tb = w * 1024 + j * 4096 + (t & 63) * 16;
      int row = tb >> 6, gd = (tb >> 4) & 3;
      asrcH[j] = (const u16*)Ap + (size_t)(tileM + row) * K + ((gd ^ ((row >> 1) & 3)) << 3);
      adstH[j] = As16 + w * 512 + j * 2048;
    }
  }

  f32x4 acc[4][4];
#pragma unroll
  for (int m = 0; m < 4; ++m)
#pragma unroll
    for (int n = 0; n < 4; ++n) {
      f32x4 z = {0.f, 0.f, 0.f, 0.f};
      acc[m][n] = z;
    }

  for (int k0 = 0; k0 < K; k0 += 32) {
#pragma unroll
    for (int j = 0; j < 2; ++j) { gl16(bsrc[j], bdst[j]); bsrc[j] += 32; }
    if constexpr (AF32) {
#pragma unroll
      for (int j = 0; j < 4; ++j) { gl16(asrcF[j], adstF[j]); asrcF[j] += 32; }
    } else {
#pragma unroll
      for (int j = 0; j < 2; ++j) { gl16(asrcH[j], adstH[j]); asrcH[j] += 32; }
    }
    __syncthreads();

    bf16x8 av[4], bv[4];
#pragma unroll
    for (int m = 0; m < 4; ++m) {
      const int row = wr + m * 16 + fr;
      if constexpr (AF32) {
        const int g0 = (2 * fg) ^ (row & 7);
        const int g1 = (2 * fg + 1) ^ (row & 7);
        float4 p0 = *(const float4*)(Asf + row * 32 + g0 * 4);
        float4 p1 = *(const float4*)(Asf + row * 32 + g1 * 4);
        uint4 u;
        u.x = cvtpk(p0.x, p0.y); u.y = cvtpk(p0.z, p0.w);
        u.z = cvtpk(p1.x, p1.y); u.w = cvtpk(p1.z, p1.w);
        av[m] = __builtin_bit_cast(bf16x8, u);
      } else {
        const int g = fg ^ ((row >> 1) & 3);
        av[m] = __builtin_bit_cast(bf16x8, *(const u16x8*)(As16 + row * 32 + g * 8));
      }
    }
#pragma unroll
    for (int n = 0; n < 4; ++n) {
      const int row = wc + n * 16 + fr;
      const int g = fg ^ ((row >> 1) & 3);
      bv[n] = __builtin_bit_cast(bf16x8, *(const u16x8*)(Bs + row * 32 + g * 8));
    }
#pragma unroll
    for (int m = 0; m < 4; ++m)
#pragma unroll
      for (int n = 0; n < 4; ++n)
        acc[m][n] = mfma16(av[m], bv[n], acc[m][n]);
    __syncthreads();
  }

#pragma unroll
  for (int m = 0; m < 4; ++m) {
#pragma unroll
    for (int n = 0; n < 4; ++n) {
      const int gcol = tileN + wc + n * 16 + fr;
      const int growb = tileM + wr + m * 16 + fg * 4;
#pragma unroll
      for (int r = 0; r < 4; ++r) {
        const int grow = growb + r;
        float v = acc[m][n][r];
        if constexpr (EPI == EPI_GATES) {
          v += bias[gcol];   // b_ih + b_hh folded here
          ((u16*)Cp)[(size_t)grow * ldc + gcol] = f2b(v);
        } else if constexpr (EPI == EPI_H1) {
          v += bias[(grow >> 7) * 256 + gcol];
          v = fmaxf(v, 0.f);
          ((u16*)Cp)[(size_t)grow * ldc + gcol] = f2b(v);
        } else if constexpr (EPI == EPI_H2) {
          v += bias[gcol];
          v = fmaxf(v, 0.f);
          ((u16*)Cp)[(size_t)grow * ldc + gcol] = f2b(v);
        } else {
          v += bias[gcol];
          ((float*)Cp)[(size_t)grow * ldc + gcol] = sigf(v);
        }
      }
    }
  }
}

// ---------------- fused LSTM scan + encoder + VQ + p1 ----------------
// 640 threads (10 waves), one block per batch. W_hh i8 in LDS ([jb][row]
// uint4) + tail dwords in kh2 regs. 3-way k-split (R16 structure, 225us).
// This round: in-loop barriers are raw lgkmcnt-only (bar_lds) so the gate
// prefetch global loads stay in flight across the step boundary instead of
// being drained by __syncthreads' vmcnt(0). Bit-identical math.
__global__ __launch_bounds__(NTHR) void lstm_enc(
    const u16* __restrict__ gates, const uint4* __restrict__ W4g,
    const uint4* __restrict__ WregG,
    const float* __restrict__ Wenc, const float* __restrict__ b_enc,
    const float* __restrict__ emb, const float* __restrict__ W1,
    const float* __restrict__ b1, const float* __restrict__ noise,
    float* __restrict__ p1) {
  extern __shared__ __attribute__((aligned(16))) char dynsm[];
  uint4* W4 = (uint4*)dynsm;                       // [12*800] uint4 (i8)
  __shared__ __attribute__((aligned(16))) unsigned sh_hq[2][56];  // h i8, dbuf, pad 0
  __shared__ __attribute__((aligned(16))) char sh_un[2 * 208 * 16];  // sh_p / rd+ri
  __shared__ __attribute__((aligned(16))) float sh_hf[HID];
  __shared__ __attribute__((aligned(16))) float sh_ze[LATENT];
  __shared__ float sh_zq[LATENT];
  int (*sh_p)[208][4] = (int(*)[208][4])sh_un;   // [2][208][4]
  float* sh_rd = (float*)sh_un;                  // [640]
  int* sh_ri = (int*)(sh_un + NTHR * 4);         // [640]
  const int r = threadIdx.x;
  const int b = blockIdx.x;
  const bool act = (r < 600);
  const int kh = r / 200;          // 0,1,2 (3 for idle tail)
  const int u = r - kh * 200;
  const bool lo = (kh == 0);

  // stage W4 into LDS (9600 uint4, coalesced; L2-resident source)
  for (int i = r; i < W4_UINT4; i += NTHR) W4[i] = W4g[i];
  uint4 wt0 = {0, 0, 0, 0}, wt1 = {0, 0, 0, 0};
  if (kh == 2) { wt0 = WregG[u * 2]; wt1 = WregG[u * 2 + 1]; }
  if (r < 56) { sh_hq[0][r] = 0; sh_hq[1][r] = 0; }
  float c = 0.f, hlast = 0.f;
  const u16* gp = gates + (size_t)b * TLEN * LDG + u;
  float gv0 = 0.f, gv1 = 0.f, gv2 = 0.f, gv3 = 0.f;
  if (lo) {
    gv0 = b2f(gp[0]); gv1 = b2f(gp[200]);
    gv2 = b2f(gp[400]); gv3 = b2f(gp[600]);
  }
  __syncthreads();   // full drain: W4 staging (global_load_lds) resident

  for (int t = 0; t < TLEN; ++t) {
    gp += LDG;
    float gn0 = 0.f, gn1 = 0.f, gn2 = 0.f, gn3 = 0.f;
    if (lo && t + 1 < TLEN) {
      gn0 = b2f(gp[0]); gn1 = b2f(gp[200]);
      gn2 = b2f(gp[400]); gn3 = b2f(gp[600]);
    }
    const int cur = t & 1, nxt = cur ^ 1;

    int a0 = 0, a1 = 0, a2 = 0, a3 = 0;
    if (act) {
      unsigned hd[16];
#pragma unroll
      for (int j = 0; j < 4; ++j) {
        uint4 v = ((const uint4*)sh_hq[cur])[kh * 4 + j];
        hd[4 * j + 0] = v.x; hd[4 * j + 1] = v.y;
        hd[4 * j + 2] = v.z; hd[4 * j + 3] = v.w;
      }
#pragma unroll
      for (int j = 0; j < 4; ++j) {
        const int jb = kh * 4 + j;
        uint4 w0 = W4[jb * 800 + u];
        uint4 w1 = W4[jb * 800 + 200 + u];
        uint4 w2 = W4[jb * 800 + 400 + u];
        uint4 w3 = W4[jb * 800 + 600 + u];
#pragma unroll
        for (int e = 0; e < 4; ++e) {
          unsigned h = hd[j * 4 + e];
          a0 = dot4((&w0.x)[e], h, a0);
          a1 = dot4((&w1.x)[e], h, a1);
          a2 = dot4((&w2.x)[e], h, a2);
          a3 = dot4((&w3.x)[e], h, a3);
        }
      }
      if (kh == 2) {
        // tail k 192..199 from registers
        uint2 ht = *(const uint2*)&sh_hq[cur][48];
        a0 = dot4(wt0.x, ht.x, a0); a0 = dot4(wt0.y, ht.y, a0);
        a1 = dot4(wt0.z, ht.x, a1); a1 = dot4(wt0.w, ht.y, a1);
        a2 = dot4(wt1.x, ht.x, a2); a2 = dot4(wt1.y, ht.y, a2);
        a3 = dot4(wt1.z, ht.x, a3); a3 = dot4(wt1.w, ht.y, a3);
      }
      if (kh) {
        int4 pv; pv.x = a0; pv.y = a1; pv.z = a2; pv.w = a3;
        *(int4*)&sh_p[kh - 1][u][0] = pv;
      }
    }
    bar_lds();   // partials visible; gate prefetch stays in flight
    if (lo) {
      int4 p0 = *(const int4*)&sh_p[0][u][0];
      int4 p1v = *(const int4*)&sh_p[1][u][0];
      float gi = gv0 + (float)(a0 + p0.x + p1v.x) * ISCL;
      float gf = gv1 + (float)(a1 + p0.y + p1v.y) * ISCL;
      float gg = gv2 + (float)(a2 + p0.z + p1v.z) * ISCL;
      float go = gv3 + (float)(a3 + p0.w + p1v.w) * ISCL;
      c = sigf(gf) * c + sigf(gi) * tanh_fast(gg);
      hlast = sigf(go) * tanh_fast(c);
      ((char*)sh_hq[nxt])[u] = (char)__float2int_rn(hlast * HSCL);
    }
    bar_lds();   // h(t+1) visible; sh_p free for reuse
    gv0 = gn0; gv1 = gn1; gv2 = gn2; gv3 = gn3;
  }

  if (lo) sh_hf[u] = hlast;
  __syncthreads();

  // encoder: z_e = h @ Wenc^T + b_enc
  if (r < LATENT) {
    float z = b_enc[r];
#pragma unroll 4
    for (int k = 0; k < HID; ++k) z = fmaf(Wenc[(size_t)r * HID + k], sh_hf[k], z);
    sh_ze[r] = z;
  }
  __syncthreads();

  // VQ: argmin_k ||e_k||^2 - 2 z_e . e_k
  float best = INFINITY; int bi = 0;
  for (int k = r; k < NCODES; k += NTHR) {
    float d = 0.f;
#pragma unroll
    for (int q = 0; q < LATENT / 4; ++q) {
      float4 e = *(const float4*)&emb[(size_t)k * LATENT + q * 4];
      float4 z = *(const float4*)&sh_ze[q * 4];
      d += e.x * (e.x - 2.f * z.x) + e.y * (e.y - 2.f * z.y)
         + e.z * (e.z - 2.f * z.z) + e.w * (e.w - 2.f * z.w);
    }
    if (d < best) { best = d; bi = k; }
  }
  sh_rd[r] = best; sh_ri[r] = bi;
  __syncthreads();
  for (int s = 512; s > 0; s >>= 1) {
    if (r < s && r + s < NTHR) {
      float od = sh_rd[r + s]; int oi = sh_ri[r + s];
      if (od < sh_rd[r] || (od == sh_rd[r] && oi < sh_ri[r])) { sh_rd[r] = od; sh_ri[r] = oi; }
    }
    __syncthreads();
  }
  const int kmin = sh_ri[0];
  if (r < LATENT) sh_zq[r] = emb[(size_t)kmin * LATENT + r];
  __syncthreads();

  // p1[b][j] = b1 + W1[:,0:128].zq + W1[:,1664:2432].noise  (pad cols 200..255 = 0)
  if (r < 256) {
    float v = 0.f;
    if (r < HID) {
      v = b1[r];
      const float* wrow = W1 + (size_t)r * 2432;
#pragma unroll 4
      for (int d = 0; d < LATENT; ++d) v = fmaf(wrow[d], sh_zq[d], v);
      const float* nz = noise + (size_t)b * DIN;
#pragma unroll 4
      for (int d = 0; d < DIN; ++d) v = fmaf(wrow[1664 + d], nz[d], v);
    }
    p1[b * 256 + r] = v;
  }
}

// ---------------- host ----------------
extern "C" void kernel_launch(void* const* d_in, const int* in_sizes, int n_in,
                              void* d_out, int out_size, void* d_ws, size_t ws_size,
                              hipStream_t stream) {
  const float* x     = (const float*)d_in[0];
  const float* cond  = (const float*)d_in[1];
  const float* noise = (const float*)d_in[2];
  const float* W_ih  = (const float*)d_in[3];
  const float* W_hh  = (const float*)d_in[4];
  const float* b_ih  = (const float*)d_in[5];
  const float* b_hh  = (const float*)d_in[6];
  const float* W_enc = (const float*)d_in[7];
  const float* b_enc = (const float*)d_in[8];
  const float* emb   = (const float*)d_in[9];
  const float* W1    = (const float*)d_in[10];
  const float* b1    = (const float*)d_in[11];
  const float* W2    = (const float*)d_in[12];
  const float* b2    = (const float*)d_in[13];
  const float* W3    = (const float*)d_in[14];
  const float* b3    = (const float*)d_in[15];

  char* ws = (char*)d_ws;
  size_t off = 0;
  auto alloc = [&](size_t bytes) -> void* {
    void* p = ws + off; off += (bytes + 255) & ~(size_t)255; return p;
  };
  u16*      W_ihb = (u16*)alloc((size_t)896 * 768 * 2);
  u16*      W1cb  = (u16*)alloc((size_t)256 * 1536 * 2);
  u16*      W2b   = (u16*)alloc((size_t)512 * 256 * 2);
  u16*      W3b   = (u16*)alloc((size_t)768 * 512 * 2);
  float*    b2p   = (float*)alloc(512 * 4);
  unsigned* W4    = (unsigned*)alloc((size_t)W4_BYTES);
  unsigned* Wreg  = (unsigned*)alloc((size_t)200 * 8 * 4);
  float*    biasc = (float*)alloc(LDG * 4);
  u16*      gates = (u16*)alloc((size_t)MROWS * LDG * 2);
  float*    p1    = (float*)alloc(256 * 256 * 4);
  u16*      h1    = (u16*)alloc((size_t)MROWS * LDH1 * 2);
  u16*      h2    = (u16*)alloc((size_t)MROWS * LDH2 * 2);

  cvt_pad<<<dim3((896 * 768 + 255) / 256), 256, 0, stream>>>(W_ih, W_ihb, 800, 768, 768, 0, 896, 768);
  cvt_pad<<<dim3((256 * 1536 + 255) / 256), 256, 0, stream>>>(W1, W1cb, 200, 1536, 2432, 128, 256, 1536);
  cvt_pad<<<dim3((512 * 256 + 255) / 256), 256, 0, stream>>>(W2, W2b, 400, 200, 200, 0, 512, 256);
  cvt_pad<<<dim3((768 * 512 + 255) / 256), 256, 0, stream>>>(W3, W3b, 768, 400, 400, 0, 768, 512);
  pad_f32<<<dim3(2), 256, 0, stream>>>(b2, b2p, 400, 512);
  pack_whh_i8<<<dim3((800 * 50 + 255) / 256), 256, 0, stream>>>(W_hh, W4, Wreg, b_ih, b_hh, biasc);

  // gates = x @ W_ih^T + (b_ih + b_hh), bf16 out, ld 896  (1792 blocks, %8==0)
  gemm_bf16<true, EPI_GATES><<<dim3((LDG / 128) * (MROWS / 128)), 256, 0, stream>>>(
      x, W_ihb, gates, 768, LDG, biasc, LDG / 128);

  // LSTM scan + encoder + VQ + p1 (W_hh in dynamic LDS, i8; 640 thr, 3-way k-split)
  static bool attr_set = false;
  if (!attr_set) {
    (void)hipFuncSetAttribute((const void*)lstm_enc,
                              hipFuncAttributeMaxDynamicSharedMemorySize, W4_BYTES);
    attr_set = true;
  }
  lstm_enc<<<dim3(NB), NTHR, W4_BYTES, stream>>>(gates, (const uint4*)W4, (const uint4*)Wreg,
                                                 W_enc, b_enc, emb, W1, b1, noise, p1);

  // h1 = relu(cond @ W1c^T + p1[b])   (512 blocks)
  gemm_bf16<true, EPI_H1><<<dim3((LDH1 / 128) * (MROWS / 128)), 256, 0, stream>>>(
      cond, W1cb, h1, DCOND, LDH1, p1, LDH1 / 128);
  // h2 = relu(h1 @ W2^T + b2)   (1024 blocks)
  gemm_bf16<false, EPI_H2><<<dim3((LDH2 / 128) * (MROWS / 128)), 256, 0, stream>>>(
      h1, W2b, h2, LDH1, LDH2, b2p, LDH2 / 128);
  // out = sigmoid(h2 @ W3^T + b3)   (1536 blocks)
  gemm_bf16<false, EPI_OUT><<<dim3((NOUT / 128) * (MROWS / 128)), 256, 0, stream>>>(
      h2, W3b, (float*)d_out, LDH2, NOUT, b3, NOUT / 128);
}